// Round 1
// baseline (122.942 us; speedup 1.0000x reference)
//
#include <hip/hip_runtime.h>
#include <hip/hip_bf16.h>

#define S_LEN 2048
#define B_SZ 2
#define IN_DIM 512
#define OUT_DIM 768
#define KWIN 31
#define PAD 15
#define NGROUP 6
#define DHEAD 128
#define M_TOT 4096          // B*S
#define N_TOT 2304          // 3*OUT
#define KSTEPS 24           // (3*512)/64
#define KSTRIDE 130         // LDS row stride (floats) for k/v tiles: 130j mod 32 = 2j -> 2-way max (free)

typedef __attribute__((ext_vector_type(8))) __bf16 bf16x8;
typedef __attribute__((ext_vector_type(4))) float f32x4;

static __device__ __forceinline__ unsigned short f2bf(float f) {
  unsigned int u = __float_as_uint(f);
  unsigned int r = (u + 0x7fffu + ((u >> 16) & 1u)) >> 16;   // RNE
  return (unsigned short)r;
}
static __device__ __forceinline__ float bf2f(unsigned short h) {
  return __uint_as_float(((unsigned int)h) << 16);
}

// ---- prep: split x into bf16 hi/lo (exact grid: 2048 blocks x 256 = 524288 float4s)
__global__ __launch_bounds__(256) void split_x_kernel(const float* __restrict__ x,
    unsigned short* __restrict__ hi, unsigned short* __restrict__ lo) {
  int i = blockIdx.x * 256 + threadIdx.x;
  float4 v = ((const float4*)x)[i];
  unsigned short h0 = f2bf(v.x), h1 = f2bf(v.y), h2 = f2bf(v.z), h3 = f2bf(v.w);
  ((ushort4*)hi)[i] = make_ushort4(h0, h1, h2, h3);
  ((ushort4*)lo)[i] = make_ushort4(f2bf(v.x - bf2f(h0)), f2bf(v.y - bf2f(h1)),
                                   f2bf(v.z - bf2f(h2)), f2bf(v.w - bf2f(h3)));
}

// ---- prep: split concat(Wq,Wk,Wv) (each 768x512 row-major) into bf16 hi/lo (1152 blocks)
__global__ __launch_bounds__(256) void split_w_kernel(const float* __restrict__ Wq,
    const float* __restrict__ Wk, const float* __restrict__ Wv,
    unsigned short* __restrict__ hi, unsigned short* __restrict__ lo) {
  int i = blockIdx.x * 256 + threadIdx.x;      // float4 index over 3*768*512 elems
  int e = i * 4;
  const int per = OUT_DIM * IN_DIM;            // 393216
  const float* src = (e < per) ? Wq : (e < 2 * per) ? Wk : Wv;
  int rem = (e < per) ? e : (e < 2 * per) ? e - per : e - 2 * per;
  float4 v = *(const float4*)(src + rem);
  unsigned short h0 = f2bf(v.x), h1 = f2bf(v.y), h2 = f2bf(v.z), h3 = f2bf(v.w);
  ((ushort4*)hi)[i] = make_ushort4(h0, h1, h2, h3);
  ((ushort4*)lo)[i] = make_ushort4(f2bf(v.x - bf2f(h0)), f2bf(v.y - bf2f(h1)),
                                   f2bf(v.z - bf2f(h2)), f2bf(v.w - bf2f(h3)));
}

// ---- prep: relT[kk][o] = rel[o][kk]  (93 blocks x 256 = 23808 exact)
__global__ __launch_bounds__(256) void relT_kernel(const float* __restrict__ rel,
                                                   float* __restrict__ relT) {
  int idx = blockIdx.x * 256 + threadIdx.x;    // = kk*768 + o
  int kk = idx / OUT_DIM;
  int o = idx - kk * OUT_DIM;
  relT[idx] = rel[o * KWIN + kk];
}

// ---- GEMM: C[4096][2304] f32 = sum of 3 split-bf16 terms (K-extended to 1536)
// m97-style: 128x128 tile, 4 waves (each 64x64 = 4x4 frags), 16x16x32 bf16 MFMA, BK=64
__global__ __launch_bounds__(256) void gemm_kernel(
    const unsigned short* __restrict__ Ahi, const unsigned short* __restrict__ Alo,
    const unsigned short* __restrict__ Whi, const unsigned short* __restrict__ Wlo,
    float* __restrict__ C) {
  __shared__ unsigned short At[128 * 64];
  __shared__ unsigned short Bt[128 * 64];
  const int tid = threadIdx.x;
  const int wave = tid >> 6, lane = tid & 63;
  const int bm = blockIdx.x & 31;   // 32 row tiles
  const int bn = blockIdx.x >> 5;   // 18 col tiles
  const int row0 = bm * 128, col0 = bn * 128;
  const int wm = (wave >> 1) * 64, wn = (wave & 1) * 64;

  f32x4 acc[4][4] = {};

  const int t8 = tid & 7;           // 8-elem chunk within 64-wide K row
  const int trA = tid >> 3;         // 0..31: row within 32-row chunk

  for (int ks = 0; ks < KSTEPS; ++ks) {
    const int term = ks >> 3;                 // 0: hi*hi, 1: lo*hi, 2: hi*lo
    const int kloc = (ks & 7) * 64;
    const unsigned short* Asrc = (term == 1) ? Alo : Ahi;
    const unsigned short* Bsrc = (term == 2) ? Wlo : Whi;
    __syncthreads();                           // protect LDS from previous compute reads
#pragma unroll
    for (int i = 0; i < 4; ++i) {
      const unsigned short* ga = Asrc + (size_t)(row0 + i * 32 + trA) * IN_DIM + kloc + t8 * 8;
      __builtin_amdgcn_global_load_lds((const __attribute__((address_space(1))) void*)ga,
          (__attribute__((address_space(3))) void*)(At + i * 2048 + wave * 512), 16, 0, 0);
      const unsigned short* gb = Bsrc + (size_t)(col0 + i * 32 + trA) * IN_DIM + kloc + t8 * 8;
      __builtin_amdgcn_global_load_lds((const __attribute__((address_space(1))) void*)gb,
          (__attribute__((address_space(3))) void*)(Bt + i * 2048 + wave * 512), 16, 0, 0);
    }
    __syncthreads();                           // drain vmcnt + barrier
    const int lr = lane & 15;
    const int lk8 = (lane >> 4) * 8;
#pragma unroll
    for (int ksub = 0; ksub < 2; ++ksub) {
      const int kof = ksub * 32 + lk8;
      bf16x8 af[4], bfr[4];
#pragma unroll
      for (int mi = 0; mi < 4; ++mi)
        af[mi] = *(const bf16x8*)(At + (wm + mi * 16 + lr) * 64 + kof);
#pragma unroll
      for (int ni = 0; ni < 4; ++ni)
        bfr[ni] = *(const bf16x8*)(Bt + (wn + ni * 16 + lr) * 64 + kof);
#pragma unroll
      for (int mi = 0; mi < 4; ++mi)
#pragma unroll
        for (int ni = 0; ni < 4; ++ni)
          acc[mi][ni] = __builtin_amdgcn_mfma_f32_16x16x32_bf16(af[mi], bfr[ni], acc[mi][ni], 0, 0, 0);
    }
  }
  // epilogue: C/D layout col=lane&15, row=(lane>>4)*4+j  [m89/m91 verified]
  const int elr = lane & 15, elg = (lane >> 4) * 4;
#pragma unroll
  for (int mi = 0; mi < 4; ++mi)
#pragma unroll
    for (int ni = 0; ni < 4; ++ni) {
      size_t base = (size_t)(row0 + wm + mi * 16 + elg) * N_TOT + (col0 + wn + ni * 16 + elr);
#pragma unroll
      for (int j = 0; j < 4; ++j)
        C[base + (size_t)j * N_TOT] = acc[mi][ni][j];
    }
}

// ---- fused banded attention: per block = (b, g, 32-row s-tile); fp32 throughout
__global__ __launch_bounds__(256) void attn_kernel(
    const float* __restrict__ qkv, const float* __restrict__ relT,
    float* __restrict__ out, float* __restrict__ attn_out) {
  __shared__ float klds[93 * KSTRIDE];   // rows 0..61: k window; 62..92: rel rows; reused for v
  __shared__ float qlds[32 * 128];       // q rows; attn written in-place after softmax
  const int tid = threadIdx.x;
  const int wave = tid >> 6, lane = tid & 63;
  const int bid = blockIdx.x;            // 2*6*64 = 768
  const int tile = bid & 63;
  const int g = (bid >> 6) % NGROUP;
  const int b = bid / (64 * NGROUP);
  const int s0 = tile * 32;
  const size_t rowbase = (size_t)b * S_LEN;

  // stage q: 32 x 128 f32
#pragma unroll
  for (int p = 0; p < 4; ++p) {
    int fi = p * 256 + tid;              // float4 index 0..1023
    int r = fi >> 5;
    int c = (fi & 31) * 4;
    float4 v = *(const float4*)(qkv + (rowbase + s0 + r) * N_TOT + g * DHEAD + c);
    *(float4*)(qlds + r * 128 + c) = v;  // stride 128 -> 16B aligned
  }
  // stage k window (62 rows, zero outside [0,S)) + 31 rel rows
  {
    int rsub = tid >> 5;
    int c = (tid & 31) * 4;
    for (int r0 = 0; r0 < 93; r0 += 8) {
      int r = r0 + rsub;
      if (r < 93) {
        float4 v = make_float4(0.f, 0.f, 0.f, 0.f);
        if (r < 62) {
          int j = s0 - PAD + r;
          if (j >= 0 && j < S_LEN)
            v = *(const float4*)(qkv + (rowbase + j) * N_TOT + OUT_DIM + g * DHEAD + c);
        } else {
          int kk = r - 62;
          v = *(const float4*)(relT + kk * OUT_DIM + g * DHEAD + c);
        }
        float* dst = klds + r * KSTRIDE + c;   // stride 130: not 16B aligned for odd r
        dst[0] = v.x; dst[1] = v.y; dst[2] = v.z; dst[3] = v.w;
      }
    }
  }
  __syncthreads();

  // energy + softmax: lane = kk (0..30), half-wave pairs handle (si, si+1)
  const int kkl = lane & 31;
  const int half = lane >> 5;
  const int kkc = (kkl < 31) ? kkl : 30;   // clamp for addressing only
#pragma unroll
  for (int p = 0; p < 4; ++p) {
    const int si = p * 8 + wave * 2 + half;
    const float2* q2 = (const float2*)(qlds + si * 128);
    const float2* k2 = (const float2*)(klds + (si + kkc) * KSTRIDE);
    const float2* r2 = (const float2*)(klds + (62 + kkc) * KSTRIDE);
    float e = 0.f;
#pragma unroll 8
    for (int t = 0; t < 64; ++t) {
      float2 qv = q2[t], kv = k2[t], rv = r2[t];
      e = fmaf(qv.x, kv.x + rv.x, e);
      e = fmaf(qv.y, kv.y + rv.y, e);
    }
    if (kkl == 31) e = -INFINITY;
    float m = e;
#pragma unroll
    for (int off = 16; off > 0; off >>= 1) m = fmaxf(m, __shfl_xor(m, off, 32));
    float pr = __expf(e - m);
    float sum = pr;
#pragma unroll
    for (int off = 16; off > 0; off >>= 1) sum += __shfl_xor(sum, off, 32);
    float a = pr / sum;
    if (kkl < 31) {
      qlds[si * 128 + kkl] = a;   // own row: safe, reads for this row are done
      attn_out[((rowbase + s0 + si) * NGROUP + g) * KWIN + kkl] = a;
    }
  }
  __syncthreads();

  // restage v into klds rows 0..61 (f32, zero outside [0,S))
  {
    int rsub = tid >> 5;
    int c = (tid & 31) * 4;
    for (int r0 = 0; r0 < 62; r0 += 8) {
      int r = r0 + rsub;
      if (r < 62) {
        int j = s0 - PAD + r;
        float4 v = make_float4(0.f, 0.f, 0.f, 0.f);
        if (j >= 0 && j < S_LEN)
          v = *(const float4*)(qkv + (rowbase + j) * N_TOT + 2 * OUT_DIM + g * DHEAD + c);
        float* dst = klds + r * KSTRIDE + c;
        dst[0] = v.x; dst[1] = v.y; dst[2] = v.z; dst[3] = v.w;
      }
    }
  }
  __syncthreads();

  // PV: wave per s-row, lane = d, 2 outputs per lane
#pragma unroll
  for (int it = 0; it < 8; ++it) {
    const int si = it * 4 + wave;
    const float* ar = qlds + si * 128;
    float o0 = 0.f, o1 = 0.f;
#pragma unroll
    for (int kk = 0; kk < KWIN; ++kk) {
      float a = ar[kk];                      // LDS broadcast
      const float* vr = klds + (si + kk) * KSTRIDE;
      o0 = fmaf(a, vr[lane], o0);
      o1 = fmaf(a, vr[lane + 64], o1);
    }
    size_t ob = (rowbase + s0 + si) * OUT_DIM + g * DHEAD;
    out[ob + lane] = o0;
    out[ob + 64 + lane] = o1;
  }
}

extern "C" void kernel_launch(void* const* d_in, const int* in_sizes, int n_in,
                              void* d_out, int out_size, void* d_ws, size_t ws_size,
                              hipStream_t stream) {
  const float* x   = (const float*)d_in[0];
  const float* Wq  = (const float*)d_in[1];
  const float* Wk  = (const float*)d_in[2];
  const float* Wv  = (const float*)d_in[3];
  const float* rel = (const float*)d_in[4];

  // workspace layout (bytes): Ahi 4MB | Alo 4MB | WhiT 2.25MB | WloT 2.25MB | relT | qkv 36MB
  char* ws = (char*)d_ws;
  unsigned short* Ahi  = (unsigned short*)(ws);
  unsigned short* Alo  = (unsigned short*)(ws + 4194304);
  unsigned short* Whi  = (unsigned short*)(ws + 8388608);
  unsigned short* Wlo  = (unsigned short*)(ws + 10747904);
  float*          relT = (float*)(ws + 13107200);
  float*          qkv  = (float*)(ws + 13202432);   // 4096 x 2304 f32

  float* outp = (float*)d_out;
  float* attn = outp + (size_t)B_SZ * S_LEN * OUT_DIM;

  split_x_kernel<<<2048, 256, 0, stream>>>(x, Ahi, Alo);
  split_w_kernel<<<1152, 256, 0, stream>>>(Wq, Wk, Wv, Whi, Wlo);
  relT_kernel<<<93, 256, 0, stream>>>(rel, relT);
  gemm_kernel<<<576, 256, 0, stream>>>(Ahi, Alo, Whi, Wlo, qkv);
  attn_kernel<<<768, 256, 0, stream>>>(qkv, relT, outp, attn);
}

// Round 2
// 90.632 us; speedup vs baseline: 1.3565x; 1.3565x over previous
//
#include <hip/hip_runtime.h>
#include <hip/hip_bf16.h>

#define S_LEN 2048
#define B_SZ 2
#define IN_DIM 512
#define OUT_DIM 768
#define KWIN 31
#define PAD 15
#define NGROUP 6
#define DHEAD 128
#define M_TOT 4096          // B*S
#define N_TOT 2304          // 3*OUT
#define KSTRIDE 130         // attn LDS row stride

typedef __attribute__((ext_vector_type(8))) __bf16 bf16x8;
typedef __attribute__((ext_vector_type(4))) float f32x4;

static __device__ __forceinline__ unsigned short f2bf(float f) {
  unsigned int u = __float_as_uint(f);
  unsigned int r = (u + 0x7fffu + ((u >> 16) & 1u)) >> 16;   // RNE
  return (unsigned short)r;
}
static __device__ __forceinline__ float bf2f(unsigned short h) {
  return __uint_as_float(((unsigned int)h) << 16);
}

// ---- prep: split x into bf16 hi/lo
__global__ __launch_bounds__(256) void split_x_kernel(const float* __restrict__ x,
    unsigned short* __restrict__ hi, unsigned short* __restrict__ lo) {
  int i = blockIdx.x * 256 + threadIdx.x;
  float4 v = ((const float4*)x)[i];
  unsigned short h0 = f2bf(v.x), h1 = f2bf(v.y), h2 = f2bf(v.z), h3 = f2bf(v.w);
  ((ushort4*)hi)[i] = make_ushort4(h0, h1, h2, h3);
  ((ushort4*)lo)[i] = make_ushort4(f2bf(v.x - bf2f(h0)), f2bf(v.y - bf2f(h1)),
                                   f2bf(v.z - bf2f(h2)), f2bf(v.w - bf2f(h3)));
}

// ---- prep: split concat(Wq,Wk,Wv) into bf16 hi/lo
__global__ __launch_bounds__(256) void split_w_kernel(const float* __restrict__ Wq,
    const float* __restrict__ Wk, const float* __restrict__ Wv,
    unsigned short* __restrict__ hi, unsigned short* __restrict__ lo) {
  int i = blockIdx.x * 256 + threadIdx.x;
  int e = i * 4;
  const int per = OUT_DIM * IN_DIM;
  const float* src = (e < per) ? Wq : (e < 2 * per) ? Wk : Wv;
  int rem = (e < per) ? e : (e < 2 * per) ? e - per : e - 2 * per;
  float4 v = *(const float4*)(src + rem);
  unsigned short h0 = f2bf(v.x), h1 = f2bf(v.y), h2 = f2bf(v.z), h3 = f2bf(v.w);
  ((ushort4*)hi)[i] = make_ushort4(h0, h1, h2, h3);
  ((ushort4*)lo)[i] = make_ushort4(f2bf(v.x - bf2f(h0)), f2bf(v.y - bf2f(h1)),
                                   f2bf(v.z - bf2f(h2)), f2bf(v.w - bf2f(h3)));
}

// ---- prep: relT[kk][o] = rel[o][kk]
__global__ __launch_bounds__(256) void relT_kernel(const float* __restrict__ rel,
                                                   float* __restrict__ relT) {
  int idx = blockIdx.x * 256 + threadIdx.x;
  int kk = idx / OUT_DIM;
  int o = idx - kk * OUT_DIM;
  relT[idx] = rel[o * KWIN + kk];
}

// =====================================================================
// GEMM: C[4096][2304] f32, split-bf16. 8-phase-style pipelined kernel.
// BM=256 BN=128 BK=64, 512 thr (8 waves: 4M x 2N, per-wave 64x64).
// 3-deep LDS slots (48KB each), prefetch 2 K-tiles ahead, vmcnt(6).
// Cols >=1536 (V) use only the hi*hi term (KT=8). Swizzle: byte ^= (row&7)<<4.
// =====================================================================
#define SLOT_BYTES 49152
#define BOFF 32768

#define READ_A(MI0) \
  _Pragma("unroll") for (int mi = 0; mi < 2; ++mi) \
  _Pragma("unroll") for (int ks = 0; ks < 2; ++ks) \
    af[(MI0) + mi][ks] = *(const bf16x8*)(base + aoffs[(MI0) + mi][ks]);

#define READ_B(NI0) \
  _Pragma("unroll") for (int ni = 0; ni < 2; ++ni) \
  _Pragma("unroll") for (int ks = 0; ks < 2; ++ks) \
    bfr[(NI0) + ni][ks] = *(const bf16x8*)(base + boffs[(NI0) + ni][ks]);

#define MFMA_Q(MI0, NI0) \
  __builtin_amdgcn_s_setprio(1); \
  _Pragma("unroll") for (int ks = 0; ks < 2; ++ks) \
  _Pragma("unroll") for (int mi = 0; mi < 2; ++mi) \
  _Pragma("unroll") for (int ni = 0; ni < 2; ++ni) \
    acc[(MI0) + mi][(NI0) + ni] = __builtin_amdgcn_mfma_f32_16x16x32_bf16( \
        af[(MI0) + mi][ks], bfr[(NI0) + ni][ks], acc[(MI0) + mi][(NI0) + ni], 0, 0, 0); \
  __builtin_amdgcn_s_setprio(0);

#define PHASE_SYNC() \
  __builtin_amdgcn_s_barrier(); \
  asm volatile("s_waitcnt lgkmcnt(0)" ::: "memory"); \
  __builtin_amdgcn_sched_barrier(0);

__global__ __launch_bounds__(512, 2) void gemm_kernel(
    const unsigned short* __restrict__ Ahi, const unsigned short* __restrict__ Alo,
    const unsigned short* __restrict__ Whi, const unsigned short* __restrict__ Wlo,
    float* __restrict__ C) {
  __shared__ unsigned short lds_u16[73728];   // 147456 B = 3 slots x 48KB
  char* ldsb = (char*)lds_u16;
  const int tid = threadIdx.x;
  const int wid = tid >> 6, lane = tid & 63;

  int bid = blockIdx.x;
  int bm, ct, KT;
  if (bid < 192) { bm = bid & 15; ct = bid >> 4; KT = 24; }          // q,k cols: 3 terms
  else { int b2 = bid - 192; bm = b2 & 15; ct = 12 + (b2 >> 4); KT = 8; }  // v cols: 1 term
  const int row0 = bm << 8, col0 = ct << 7;
  const int wm = wid >> 1, wn = wid & 1;

  // frag LDS byte offsets (relative to slot base), swizzled
  int aoffs[4][2], boffs[4][2];
#pragma unroll
  for (int mi = 0; mi < 4; ++mi) {
    int row = wm * 64 + mi * 16 + (lane & 15);       // 0..255
    int half = row >> 7, rh = row & 127;
#pragma unroll
    for (int ks = 0; ks < 2; ++ks) {
      int cb = ks * 64 + (lane >> 4) * 16;
      int O = rh * 128 + cb;
      aoffs[mi][ks] = half * 16384 + (O ^ ((O >> 3) & 0x70));
    }
  }
#pragma unroll
  for (int ni = 0; ni < 4; ++ni) {
    int row = wn * 64 + ni * 16 + (lane & 15);       // 0..127
#pragma unroll
    for (int ks = 0; ks < 2; ++ks) {
      int cb = ks * 64 + (lane >> 4) * 16;
      int O = row * 128 + cb;
      boffs[ni][ks] = BOFF + (O ^ ((O >> 3) & 0x70));
    }
  }

  // staging: linear LDS dest (tid*16), pre-swizzled global source (rule 21)
  int srow[2], scol[2];
#pragma unroll
  for (int j = 0; j < 2; ++j) {
    int L = (j << 13) | (tid << 4);
    int Ls = L ^ ((L >> 3) & 0x70);
    srow[j] = Ls >> 7;
    scol[j] = (Ls & 127) >> 1;
  }

  auto stage128 = [&](char* ldsu, const unsigned short* gsrc, int grow0, int kloc) {
#pragma unroll
    for (int j = 0; j < 2; ++j) {
      const unsigned short* g = gsrc + (size_t)(grow0 + srow[j]) * IN_DIM + kloc + scol[j];
      __builtin_amdgcn_global_load_lds((const __attribute__((address_space(1))) void*)g,
          (__attribute__((address_space(3))) void*)(ldsu + j * 8192 + wid * 1024), 16, 0, 0);
    }
  };

  f32x4 acc[4][4] = {};
  bf16x8 af[4][2], bfr[4][2];

  // prologue: stage tiles 0 and 1
  {
    char* s0 = ldsb;
    stage128(s0, Ahi, row0, 0);
    stage128(s0 + 16384, Ahi, row0 + 128, 0);
    stage128(s0 + BOFF, Whi, col0, 0);
    char* s1 = ldsb + SLOT_BYTES;
    stage128(s1, Ahi, row0, 64);
    stage128(s1 + 16384, Ahi, row0 + 128, 64);
    stage128(s1 + BOFF, Whi, col0, 64);
    asm volatile("s_waitcnt vmcnt(6)" ::: "memory");   // tile0 landed
    __builtin_amdgcn_s_barrier();
  }

  for (int t = 0; t < KT; ++t) {
    char* base = ldsb + (t % 3) * SLOT_BYTES;
    const int pt = t + 2;
    const bool pref = pt < KT;
    char* pbase = ldsb + (pt % 3) * SLOT_BYTES;
    const unsigned short* pA = Ahi;
    const unsigned short* pB = Whi;
    int pk = 0;
    if (pref) {
      int term = pt >> 3;
      pA = (term == 1) ? Alo : Ahi;
      pB = (term == 2) ? Wlo : Whi;
      pk = (pt & 7) << 6;
    }

    // phase 1: A[0..1] + B[0..1] frags; stage A-half0 of t+2; MFMA quad (0,0)
    READ_A(0)
    READ_B(0)
    if (pref) stage128(pbase, pA, row0, pk);
    PHASE_SYNC()
    MFMA_Q(0, 0)
    __builtin_amdgcn_s_barrier();

    // phase 2: B[2..3] frags; stage A-half1; MFMA quad (0,2)
    READ_B(2)
    if (pref) stage128(pbase + 16384, pA, row0 + 128, pk);
    PHASE_SYNC()
    MFMA_Q(0, 2)
    __builtin_amdgcn_s_barrier();

    // phase 3: A[2..3] frags; stage B; MFMA quad (2,0)
    READ_A(2)
    if (pref) stage128(pbase + BOFF, pB, col0, pk);
    PHASE_SYNC()
    MFMA_Q(2, 0)
    __builtin_amdgcn_s_barrier();

    // phase 4: MFMA quad (2,2); counted vmcnt (never 0 mid-loop); barrier
    MFMA_Q(2, 2)
    if (pref) { asm volatile("s_waitcnt vmcnt(6)" ::: "memory"); }
    else      { asm volatile("s_waitcnt vmcnt(0)" ::: "memory"); }
    __builtin_amdgcn_s_barrier();
  }

  // epilogue: C/D layout col=lane&15, row=(lane>>4)*4+j
  const int elr = lane & 15, elg = (lane >> 4) * 4;
#pragma unroll
  for (int mi = 0; mi < 4; ++mi)
#pragma unroll
    for (int ni = 0; ni < 4; ++ni) {
      size_t basec = (size_t)(row0 + wm * 64 + mi * 16 + elg) * N_TOT +
                     (col0 + wn * 64 + ni * 16 + elr);
#pragma unroll
      for (int j = 0; j < 4; ++j)
        C[basec + (size_t)j * N_TOT] = acc[mi][ni][j];
    }
}

// ---- fused banded attention (unchanged from round 1)
__global__ __launch_bounds__(256) void attn_kernel(
    const float* __restrict__ qkv, const float* __restrict__ relT,
    float* __restrict__ out, float* __restrict__ attn_out) {
  __shared__ float klds[93 * KSTRIDE];
  __shared__ float qlds[32 * 128];
  const int tid = threadIdx.x;
  const int wave = tid >> 6, lane = tid & 63;
  const int bid = blockIdx.x;
  const int tile = bid & 63;
  const int g = (bid >> 6) % NGROUP;
  const int b = bid / (64 * NGROUP);
  const int s0 = tile * 32;
  const size_t rowbase = (size_t)b * S_LEN;

#pragma unroll
  for (int p = 0; p < 4; ++p) {
    int fi = p * 256 + tid;
    int r = fi >> 5;
    int c = (fi & 31) * 4;
    float4 v = *(const float4*)(qkv + (rowbase + s0 + r) * N_TOT + g * DHEAD + c);
    *(float4*)(qlds + r * 128 + c) = v;
  }
  {
    int rsub = tid >> 5;
    int c = (tid & 31) * 4;
    for (int r0 = 0; r0 < 93; r0 += 8) {
      int r = r0 + rsub;
      if (r < 93) {
        float4 v = make_float4(0.f, 0.f, 0.f, 0.f);
        if (r < 62) {
          int j = s0 - PAD + r;
          if (j >= 0 && j < S_LEN)
            v = *(const float4*)(qkv + (rowbase + j) * N_TOT + OUT_DIM + g * DHEAD + c);
        } else {
          int kk = r - 62;
          v = *(const float4*)(relT + kk * OUT_DIM + g * DHEAD + c);
        }
        float* dst = klds + r * KSTRIDE + c;
        dst[0] = v.x; dst[1] = v.y; dst[2] = v.z; dst[3] = v.w;
      }
    }
  }
  __syncthreads();

  const int kkl = lane & 31;
  const int half = lane >> 5;
  const int kkc = (kkl < 31) ? kkl : 30;
#pragma unroll
  for (int p = 0; p < 4; ++p) {
    const int si = p * 8 + wave * 2 + half;
    const float2* q2 = (const float2*)(qlds + si * 128);
    const float2* k2 = (const float2*)(klds + (si + kkc) * KSTRIDE);
    const float2* r2 = (const float2*)(klds + (62 + kkc) * KSTRIDE);
    float e = 0.f;
#pragma unroll 8
    for (int t = 0; t < 64; ++t) {
      float2 qv = q2[t], kv = k2[t], rv = r2[t];
      e = fmaf(qv.x, kv.x + rv.x, e);
      e = fmaf(qv.y, kv.y + rv.y, e);
    }
    if (kkl == 31) e = -INFINITY;
    float m = e;
#pragma unroll
    for (int off = 16; off > 0; off >>= 1) m = fmaxf(m, __shfl_xor(m, off, 32));
    float pr = __expf(e - m);
    float sum = pr;
#pragma unroll
    for (int off = 16; off > 0; off >>= 1) sum += __shfl_xor(sum, off, 32);
    float a = pr / sum;
    if (kkl < 31) {
      qlds[si * 128 + kkl] = a;
      attn_out[((rowbase + s0 + si) * NGROUP + g) * KWIN + kkl] = a;
    }
  }
  __syncthreads();

  {
    int rsub = tid >> 5;
    int c = (tid & 31) * 4;
    for (int r0 = 0; r0 < 62; r0 += 8) {
      int r = r0 + rsub;
      if (r < 62) {
        int j = s0 - PAD + r;
        float4 v = make_float4(0.f, 0.f, 0.f, 0.f);
        if (j >= 0 && j < S_LEN)
          v = *(const float4*)(qkv + (rowbase + j) * N_TOT + 2 * OUT_DIM + g * DHEAD + c);
        float* dst = klds + r * KSTRIDE + c;
        dst[0] = v.x; dst[1] = v.y; dst[2] = v.z; dst[3] = v.w;
      }
    }
  }
  __syncthreads();

#pragma unroll
  for (int it = 0; it < 8; ++it) {
    const int si = it * 4 + wave;
    const float* ar = qlds + si * 128;
    float o0 = 0.f, o1 = 0.f;
#pragma unroll
    for (int kk = 0; kk < KWIN; ++kk) {
      float a = ar[kk];
      const float* vr = klds + (si + kk) * KSTRIDE;
      o0 = fmaf(a, vr[lane], o0);
      o1 = fmaf(a, vr[lane + 64], o1);
    }
    size_t ob = (rowbase + s0 + si) * OUT_DIM + g * DHEAD;
    out[ob + lane] = o0;
    out[ob + 64 + lane] = o1;
  }
}

extern "C" void kernel_launch(void* const* d_in, const int* in_sizes, int n_in,
                              void* d_out, int out_size, void* d_ws, size_t ws_size,
                              hipStream_t stream) {
  const float* x   = (const float*)d_in[0];
  const float* Wq  = (const float*)d_in[1];
  const float* Wk  = (const float*)d_in[2];
  const float* Wv  = (const float*)d_in[3];
  const float* rel = (const float*)d_in[4];

  char* ws = (char*)d_ws;
  unsigned short* Ahi  = (unsigned short*)(ws);
  unsigned short* Alo  = (unsigned short*)(ws + 4194304);
  unsigned short* Whi  = (unsigned short*)(ws + 8388608);
  unsigned short* Wlo  = (unsigned short*)(ws + 10747904);
  float*          relT = (float*)(ws + 13107200);
  float*          qkv  = (float*)(ws + 13202432);

  float* outp = (float*)d_out;
  float* attn = outp + (size_t)B_SZ * S_LEN * OUT_DIM;

  split_x_kernel<<<2048, 256, 0, stream>>>(x, Ahi, Alo);
  split_w_kernel<<<1152, 256, 0, stream>>>(Wq, Wk, Wv, Whi, Wlo);
  relT_kernel<<<93, 256, 0, stream>>>(rel, relT);
  gemm_kernel<<<288, 512, 0, stream>>>(Ahi, Alo, Whi, Wlo, qkv);
  attn_kernel<<<768, 256, 0, stream>>>(qkv, relT, outp, attn);
}

// Round 3
// 75.648 us; speedup vs baseline: 1.6252x; 1.1981x over previous
//
#include <hip/hip_runtime.h>
#include <hip/hip_bf16.h>

#define S_LEN 2048
#define B_SZ 2
#define IN_DIM 512
#define OUT_DIM 768
#define KWIN 31
#define PAD 15
#define NGROUP 6
#define DHEAD 128
#define M_TOT 4096          // B*S
#define N_TOT 2304          // 3*OUT
#define QK_W 1536           // qk hi/lo array width (q cols 0..767, k cols 768..1535)

typedef __attribute__((ext_vector_type(8))) __bf16 bf16x8;
typedef __attribute__((ext_vector_type(8))) unsigned short u16x8;
typedef __attribute__((ext_vector_type(4))) float f32x4;

static __device__ __forceinline__ unsigned short f2bf(float f) {
  unsigned int u = __float_as_uint(f);
  unsigned int r = (u + 0x7fffu + ((u >> 16) & 1u)) >> 16;   // RNE
  return (unsigned short)r;
}
static __device__ __forceinline__ float bf2f(unsigned short h) {
  return __uint_as_float(((unsigned int)h) << 16);
}

// ---- prep: split x into bf16 hi/lo
__global__ __launch_bounds__(256) void split_x_kernel(const float* __restrict__ x,
    unsigned short* __restrict__ hi, unsigned short* __restrict__ lo) {
  int i = blockIdx.x * 256 + threadIdx.x;
  float4 v = ((const float4*)x)[i];
  unsigned short h0 = f2bf(v.x), h1 = f2bf(v.y), h2 = f2bf(v.z), h3 = f2bf(v.w);
  ((ushort4*)hi)[i] = make_ushort4(h0, h1, h2, h3);
  ((ushort4*)lo)[i] = make_ushort4(f2bf(v.x - bf2f(h0)), f2bf(v.y - bf2f(h1)),
                                   f2bf(v.z - bf2f(h2)), f2bf(v.w - bf2f(h3)));
}

// ---- prep: split concat(Wq,Wk,Wv) into bf16 hi/lo
__global__ __launch_bounds__(256) void split_w_kernel(const float* __restrict__ Wq,
    const float* __restrict__ Wk, const float* __restrict__ Wv,
    unsigned short* __restrict__ hi, unsigned short* __restrict__ lo) {
  int i = blockIdx.x * 256 + threadIdx.x;
  int e = i * 4;
  const int per = OUT_DIM * IN_DIM;
  const float* src = (e < per) ? Wq : (e < 2 * per) ? Wk : Wv;
  int rem = (e < per) ? e : (e < 2 * per) ? e - per : e - 2 * per;
  float4 v = *(const float4*)(src + rem);
  unsigned short h0 = f2bf(v.x), h1 = f2bf(v.y), h2 = f2bf(v.z), h3 = f2bf(v.w);
  ((ushort4*)hi)[i] = make_ushort4(h0, h1, h2, h3);
  ((ushort4*)lo)[i] = make_ushort4(f2bf(v.x - bf2f(h0)), f2bf(v.y - bf2f(h1)),
                                   f2bf(v.z - bf2f(h2)), f2bf(v.w - bf2f(h3)));
}

// ---- prep: relT[kk][o] = rel[o][kk], split hi/lo bf16
__global__ __launch_bounds__(256) void relsplit_kernel(const float* __restrict__ rel,
    unsigned short* __restrict__ relThi, unsigned short* __restrict__ relTlo) {
  int idx = blockIdx.x * 256 + threadIdx.x;    // kk*768 + o, 93*256 = 23808 exact
  int kk = idx / OUT_DIM;
  int o = idx - kk * OUT_DIM;
  float v = rel[o * KWIN + kk];
  unsigned short h = f2bf(v);
  relThi[idx] = h;
  relTlo[idx] = f2bf(v - bf2f(h));
}

// =====================================================================
// GEMM: split-bf16, 8-phase pipelined (unchanged core from round 2).
// Epilogue: q,k cols -> bf16 hi/lo arrays; v cols -> transposed bf16 vT[d][s].
// =====================================================================
#define SLOT_BYTES 49152
#define BOFF 32768

#define READ_A(MI0) \
  _Pragma("unroll") for (int mi = 0; mi < 2; ++mi) \
  _Pragma("unroll") for (int ks = 0; ks < 2; ++ks) \
    af[(MI0) + mi][ks] = *(const bf16x8*)(base + aoffs[(MI0) + mi][ks]);

#define READ_B(NI0) \
  _Pragma("unroll") for (int ni = 0; ni < 2; ++ni) \
  _Pragma("unroll") for (int ks = 0; ks < 2; ++ks) \
    bfr[(NI0) + ni][ks] = *(const bf16x8*)(base + boffs[(NI0) + ni][ks]);

#define MFMA_Q(MI0, NI0) \
  __builtin_amdgcn_s_setprio(1); \
  _Pragma("unroll") for (int ks = 0; ks < 2; ++ks) \
  _Pragma("unroll") for (int mi = 0; mi < 2; ++mi) \
  _Pragma("unroll") for (int ni = 0; ni < 2; ++ni) \
    acc[(MI0) + mi][(NI0) + ni] = __builtin_amdgcn_mfma_f32_16x16x32_bf16( \
        af[(MI0) + mi][ks], bfr[(NI0) + ni][ks], acc[(MI0) + mi][(NI0) + ni], 0, 0, 0); \
  __builtin_amdgcn_s_setprio(0);

#define PHASE_SYNC() \
  __builtin_amdgcn_s_barrier(); \
  asm volatile("s_waitcnt lgkmcnt(0)" ::: "memory"); \
  __builtin_amdgcn_sched_barrier(0);

__global__ __launch_bounds__(512, 2) void gemm_kernel(
    const unsigned short* __restrict__ Ahi, const unsigned short* __restrict__ Alo,
    const unsigned short* __restrict__ Whi, const unsigned short* __restrict__ Wlo,
    unsigned short* __restrict__ qkhi, unsigned short* __restrict__ qklo,
    unsigned short* __restrict__ vTw) {
  __shared__ unsigned short lds_u16[73728];   // 147456 B = 3 slots x 48KB
  char* ldsb = (char*)lds_u16;
  const int tid = threadIdx.x;
  const int wid = tid >> 6, lane = tid & 63;

  int bid = blockIdx.x;
  int bm, ct, KT;
  if (bid < 192) { bm = bid & 15; ct = bid >> 4; KT = 24; }          // q,k cols: 3 terms
  else { int b2 = bid - 192; bm = b2 & 15; ct = 12 + (b2 >> 4); KT = 8; }  // v cols: 1 term
  const int row0 = bm << 8, col0 = ct << 7;
  const int wm = wid >> 1, wn = wid & 1;

  int aoffs[4][2], boffs[4][2];
#pragma unroll
  for (int mi = 0; mi < 4; ++mi) {
    int row = wm * 64 + mi * 16 + (lane & 15);
    int half = row >> 7, rh = row & 127;
#pragma unroll
    for (int ks = 0; ks < 2; ++ks) {
      int cb = ks * 64 + (lane >> 4) * 16;
      int O = rh * 128 + cb;
      aoffs[mi][ks] = half * 16384 + (O ^ ((O >> 3) & 0x70));
    }
  }
#pragma unroll
  for (int ni = 0; ni < 4; ++ni) {
    int row = wn * 64 + ni * 16 + (lane & 15);
#pragma unroll
    for (int ks = 0; ks < 2; ++ks) {
      int cb = ks * 64 + (lane >> 4) * 16;
      int O = row * 128 + cb;
      boffs[ni][ks] = BOFF + (O ^ ((O >> 3) & 0x70));
    }
  }

  int srow[2], scol[2];
#pragma unroll
  for (int j = 0; j < 2; ++j) {
    int L = (j << 13) | (tid << 4);
    int Ls = L ^ ((L >> 3) & 0x70);
    srow[j] = Ls >> 7;
    scol[j] = (Ls & 127) >> 1;
  }

  auto stage128 = [&](char* ldsu, const unsigned short* gsrc, int grow0, int kloc) {
#pragma unroll
    for (int j = 0; j < 2; ++j) {
      const unsigned short* g = gsrc + (size_t)(grow0 + srow[j]) * IN_DIM + kloc + scol[j];
      __builtin_amdgcn_global_load_lds((const __attribute__((address_space(1))) void*)g,
          (__attribute__((address_space(3))) void*)(ldsu + j * 8192 + wid * 1024), 16, 0, 0);
    }
  };

  f32x4 acc[4][4] = {};
  bf16x8 af[4][2], bfr[4][2];

  {
    char* s0 = ldsb;
    stage128(s0, Ahi, row0, 0);
    stage128(s0 + 16384, Ahi, row0 + 128, 0);
    stage128(s0 + BOFF, Whi, col0, 0);
    char* s1 = ldsb + SLOT_BYTES;
    stage128(s1, Ahi, row0, 64);
    stage128(s1 + 16384, Ahi, row0 + 128, 64);
    stage128(s1 + BOFF, Whi, col0, 64);
    asm volatile("s_waitcnt vmcnt(6)" ::: "memory");
    __builtin_amdgcn_s_barrier();
  }

  for (int t = 0; t < KT; ++t) {
    char* base = ldsb + (t % 3) * SLOT_BYTES;
    const int pt = t + 2;
    const bool pref = pt < KT;
    char* pbase = ldsb + (pt % 3) * SLOT_BYTES;
    const unsigned short* pA = Ahi;
    const unsigned short* pB = Whi;
    int pk = 0;
    if (pref) {
      int term = pt >> 3;
      pA = (term == 1) ? Alo : Ahi;
      pB = (term == 2) ? Wlo : Whi;
      pk = (pt & 7) << 6;
    }

    READ_A(0)
    READ_B(0)
    if (pref) stage128(pbase, pA, row0, pk);
    PHASE_SYNC()
    MFMA_Q(0, 0)
    __builtin_amdgcn_s_barrier();

    READ_B(2)
    if (pref) stage128(pbase + 16384, pA, row0 + 128, pk);
    PHASE_SYNC()
    MFMA_Q(0, 2)
    __builtin_amdgcn_s_barrier();

    READ_A(2)
    if (pref) stage128(pbase + BOFF, pB, col0, pk);
    PHASE_SYNC()
    MFMA_Q(2, 0)
    __builtin_amdgcn_s_barrier();

    MFMA_Q(2, 2)
    if (pref) { asm volatile("s_waitcnt vmcnt(6)" ::: "memory"); }
    else      { asm volatile("s_waitcnt vmcnt(0)" ::: "memory"); }
    __builtin_amdgcn_s_barrier();
  }

  const int elr = lane & 15, elg = (lane >> 4) * 4;
  if (ct < 12) {
    // q,k: split f32 acc -> bf16 hi/lo arrays [4096][1536]
#pragma unroll
    for (int mi = 0; mi < 4; ++mi)
#pragma unroll
      for (int ni = 0; ni < 4; ++ni) {
        int ncol = col0 + wn * 64 + ni * 16 + elr;
        size_t rbase = (size_t)(row0 + wm * 64 + mi * 16 + elg);
#pragma unroll
        for (int j = 0; j < 4; ++j) {
          float v = acc[mi][ni][j];
          unsigned short h = f2bf(v);
          size_t idx = (rbase + j) * QK_W + ncol;
          qkhi[idx] = h;
          qklo[idx] = f2bf(v - bf2f(h));
        }
      }
  } else {
    // v: transposed bf16 vT[d][srow], d = ncol-1536
#pragma unroll
    for (int mi = 0; mi < 4; ++mi)
#pragma unroll
      for (int ni = 0; ni < 4; ++ni) {
        int d = col0 - 1536 + wn * 64 + ni * 16 + elr;
        int srow = row0 + wm * 64 + mi * 16 + elg;
        ushort4 pk4;
        pk4.x = f2bf(acc[mi][ni][0]); pk4.y = f2bf(acc[mi][ni][1]);
        pk4.z = f2bf(acc[mi][ni][2]); pk4.w = f2bf(acc[mi][ni][3]);
        *(ushort4*)(vTw + (size_t)d * M_TOT + srow) = pk4;
      }
  }
}

// =====================================================================
// MFMA banded attention. Block = (b, g, 32-row tile), 256 thr (4 waves).
// LDS (80KB): Khi[96][128] @0 | Klo[96][128] @24576 | VT[128][64] @49152 |
//             Ab[32][64] @65536 | E f32[32][96] @69632
// E(32x96) = Q·[Kwin;rel;pad]^T  (3-term split bf16, rows = si, cols = window row)
// softmax -> attn_out + banded Ab (col = si+kk+1, matching VT base s0-16)
// out(32x128) = Ab·V via VT rows.
// =====================================================================
__global__ __launch_bounds__(256, 2) void attn_kernel(
    const unsigned short* __restrict__ qkhi, const unsigned short* __restrict__ qklo,
    const unsigned short* __restrict__ vT,
    const unsigned short* __restrict__ relThi, const unsigned short* __restrict__ relTlo,
    float* __restrict__ out, float* __restrict__ attn_out) {
  __shared__ __attribute__((aligned(16))) unsigned short smem[40960];   // 81920 B
  char* smb = (char*)smem;
  float* Elds = (float*)(smb + 69632);

  const int tid = threadIdx.x;
  const int wid = tid >> 6, lane = tid & 63;
  const int bid = blockIdx.x;            // 768 = 2*6*64
  const int tile = bid & 63;
  const int g = (bid >> 6) % NGROUP;
  const int b = bid / (64 * NGROUP);
  const int s0 = tile * 32;
  const size_t rowbase = (size_t)b * S_LEN;
  const int elr = lane & 15, elq = lane >> 4;

  // ---- stage K windows (hi & lo): rows 0..61 k-win, 62..92 rel, 93..95 zero
  auto stageK = [&](int ldsbase, const unsigned short* src, const unsigned short* relsrc) {
#pragma unroll
    for (int p = 0; p < 6; ++p) {
      int id = p * 256 + tid;            // 1536 chunks: row w (0..95) x 16 x 16B
      int w = id >> 4, cb = id & 15;
      u16x8 val = {};
      if (w < 62) {
        int r = s0 - 15 + w;
        if (r >= 0 && r < S_LEN)
          val = *(const u16x8*)(src + (size_t)(rowbase + r) * QK_W + OUT_DIM + g * DHEAD + cb * 8);
      } else if (w < 93) {
        val = *(const u16x8*)(relsrc + (w - 62) * OUT_DIM + g * DHEAD + cb * 8);
      }
      int O = w * 256 + cb * 16;
      O ^= (O >> 4) & 0x70;
      *(u16x8*)(smb + ldsbase + O) = val;
    }
  };
  stageK(0, qkhi, relThi);
  stageK(24576, qklo, relTlo);

  // ---- stage VT[128][64]: col jj <-> s = s0-16+jj (zero OOB); 16B-aligned base
  {
    const unsigned short* vsrc = vT + (size_t)g * DHEAD * M_TOT + (size_t)b * S_LEN;
#pragma unroll
    for (int p = 0; p < 4; ++p) {
      int id = p * 256 + tid;            // 1024 chunks: d (0..127) x 8 x 16B
      int d = id >> 3, cb = id & 7;
      int sl = s0 - 16 + cb * 8;
      const unsigned short* src = vsrc + (size_t)d * M_TOT;
      u16x8 val = {};
      if (sl >= 0 && sl + 7 < S_LEN) {
        val = *(const u16x8*)(src + sl);
      } else {
#pragma unroll
        for (int t = 0; t < 8; ++t) {
          int s = sl + t;
          if (s >= 0 && s < S_LEN) val[t] = src[s];
        }
      }
      int O = d * 128 + cb * 16;
      O ^= (O >> 3) & 0x70;
      *(u16x8*)(smb + 49152 + O) = val;
    }
  }
  // ---- zero Ab (one 16B chunk per thread; swizzle is bijective)
  {
    int O = tid * 16;
    O ^= (O >> 3) & 0x70;
    u16x8 z = {};
    *(u16x8*)(smb + 65536 + O) = z;
  }

  // ---- Q A-frags from global (per wave: its row-frag, all 4 k-steps, hi+lo)
  const int rf = wid & 1;                // E/PV row-frag of this wave
  const int cb3 = 3 * (wid >> 1);        // E col-frag base (0 or 3)
  bf16x8 qh[4], ql[4];
  {
    size_t qrow = rowbase + s0 + rf * 16 + elr;
    const unsigned short* qb  = qkhi + qrow * QK_W + g * DHEAD + elq * 8;
    const unsigned short* qb2 = qklo + qrow * QK_W + g * DHEAD + elq * 8;
#pragma unroll
    for (int ks = 0; ks < 4; ++ks) {
      qh[ks] = *(const bf16x8*)(qb + ks * 32);
      ql[ks] = *(const bf16x8*)(qb2 + ks * 32);
    }
  }
  __syncthreads();

  // ---- E = Q·K^T (3-term split), per wave 3 col-frags x 4 ksteps x 3 MFMA
#pragma unroll
  for (int cf = 0; cf < 3; ++cf) {
    int c = cb3 + cf;
    f32x4 ea = {};
#pragma unroll
    for (int ks = 0; ks < 4; ++ks) {
      int O = (c * 16 + elr) * 256 + ks * 64 + elq * 16;
      int Os = O ^ ((O >> 4) & 0x70);
      bf16x8 kh = *(const bf16x8*)(smb + Os);
      bf16x8 kl = *(const bf16x8*)(smb + 24576 + Os);
      ea = __builtin_amdgcn_mfma_f32_16x16x32_bf16(qh[ks], kh, ea, 0, 0, 0);
      ea = __builtin_amdgcn_mfma_f32_16x16x32_bf16(ql[ks], kh, ea, 0, 0, 0);
      ea = __builtin_amdgcn_mfma_f32_16x16x32_bf16(qh[ks], kl, ea, 0, 0, 0);
    }
#pragma unroll
    for (int j = 0; j < 4; ++j)
      Elds[(rf * 16 + elq * 4 + j) * 96 + c * 16 + elr] = ea[j];
  }
  __syncthreads();

  // ---- softmax (32-lane half-waves, lane = kk), write attn + banded Ab bf16
  {
    const int kkl = lane & 31;
    const int half = lane >> 5;
    const int kkc = (kkl < 31) ? kkl : 30;
#pragma unroll
    for (int p = 0; p < 4; ++p) {
      int si = p * 8 + wid * 2 + half;
      float e = Elds[si * 96 + si + kkc] + Elds[si * 96 + 62 + kkc];
      if (kkl == 31) e = -INFINITY;
      float m = e;
#pragma unroll
      for (int off = 16; off > 0; off >>= 1) m = fmaxf(m, __shfl_xor(m, off, 32));
      float pr = __expf(e - m);
      float sum = pr;
#pragma unroll
      for (int off = 16; off > 0; off >>= 1) sum += __shfl_xor(sum, off, 32);
      float a = pr / sum;
      if (kkl < 31) {
        attn_out[((rowbase + s0 + si) * NGROUP + g) * KWIN + kkl] = a;
        int O = si * 128 + (si + kkl + 1) * 2;   // jj = si+kk+1 matches VT base s0-16
        O ^= (O >> 3) & 0x70;
        *(unsigned short*)(smb + 65536 + O) = f2bf(a);
      }
    }
  }
  __syncthreads();

  // ---- PV: out(32x128) = Ab(32x64)·V ; per wave: row-frag rf, 4 d-col-frags
  {
    const int pcb = 4 * (wid >> 1);
    f32x4 pa[4] = {};
#pragma unroll
    for (int ks = 0; ks < 2; ++ks) {
      int AO = (rf * 16 + elr) * 128 + ks * 64 + elq * 16;
      AO ^= (AO >> 3) & 0x70;
      bf16x8 afr = *(const bf16x8*)(smb + 65536 + AO);
#pragma unroll
      for (int cf = 0; cf < 4; ++cf) {
        int VO = ((pcb + cf) * 16 + elr) * 128 + ks * 64 + elq * 16;
        VO ^= (VO >> 3) & 0x70;
        bf16x8 vfr = *(const bf16x8*)(smb + 49152 + VO);
        pa[cf] = __builtin_amdgcn_mfma_f32_16x16x32_bf16(afr, vfr, pa[cf], 0, 0, 0);
      }
    }
#pragma unroll
    for (int cf = 0; cf < 4; ++cf)
#pragma unroll
      for (int j = 0; j < 4; ++j)
        out[(rowbase + s0 + rf * 16 + elq * 4 + j) * OUT_DIM + g * DHEAD + pcb * 16 + cf * 16 + elr]
            = pa[cf][j];
  }
}

extern "C" void kernel_launch(void* const* d_in, const int* in_sizes, int n_in,
                              void* d_out, int out_size, void* d_ws, size_t ws_size,
                              hipStream_t stream) {
  const float* x   = (const float*)d_in[0];
  const float* Wq  = (const float*)d_in[1];
  const float* Wk  = (const float*)d_in[2];
  const float* Wv  = (const float*)d_in[3];
  const float* rel = (const float*)d_in[4];

  // ws layout (bytes):
  // Ahi 0 | Alo 4194304 | Whi 8388608 | Wlo 10747904 | relThi 13107200 |
  // relTlo 13154816 | qkhi 13202432 (12.58MB) | qklo 25785344 | vT 38368256 (6.29MB)
  char* ws = (char*)d_ws;
  unsigned short* Ahi    = (unsigned short*)(ws);
  unsigned short* Alo    = (unsigned short*)(ws + 4194304);
  unsigned short* Whi    = (unsigned short*)(ws + 8388608);
  unsigned short* Wlo    = (unsigned short*)(ws + 10747904);
  unsigned short* relThi = (unsigned short*)(ws + 13107200);
  unsigned short* relTlo = (unsigned short*)(ws + 13154816);
  unsigned short* qkhi   = (unsigned short*)(ws + 13202432);
  unsigned short* qklo   = (unsigned short*)(ws + 25785344);
  unsigned short* vTw    = (unsigned short*)(ws + 38368256);

  float* outp = (float*)d_out;
  float* attn = outp + (size_t)B_SZ * S_LEN * OUT_DIM;

  split_x_kernel<<<2048, 256, 0, stream>>>(x, Ahi, Alo);
  split_w_kernel<<<1152, 256, 0, stream>>>(Wq, Wk, Wv, Whi, Wlo);
  relsplit_kernel<<<93, 256, 0, stream>>>(rel, relThi, relTlo);
  gemm_kernel<<<288, 512, 0, stream>>>(Ahi, Alo, Whi, Wlo, qkhi, qklo, vTw);
  attn_kernel<<<768, 256, 0, stream>>>(qkhi, qklo, vTw, relThi, relTlo, outp, attn);
}

// Round 4
// 75.609 us; speedup vs baseline: 1.6260x; 1.0005x over previous
//
#include <hip/hip_runtime.h>
#include <hip/hip_bf16.h>

#define S_LEN 2048
#define B_SZ 2
#define IN_DIM 512
#define OUT_DIM 768
#define KWIN 31
#define PAD 15
#define NGROUP 6
#define DHEAD 128
#define M_TOT 4096          // B*S
#define N_TOT 2304          // 3*OUT
#define QK_W 1536           // qk hi/lo array width (q cols 0..767, k cols 768..1535)

typedef __attribute__((ext_vector_type(8))) __bf16 bf16x8;
typedef __attribute__((ext_vector_type(8))) unsigned short u16x8;
typedef __attribute__((ext_vector_type(4))) float f32x4;

static __device__ __forceinline__ unsigned short f2bf(float f) {
  unsigned int u = __float_as_uint(f);
  unsigned int r = (u + 0x7fffu + ((u >> 16) & 1u)) >> 16;   // RNE
  return (unsigned short)r;
}
static __device__ __forceinline__ float bf2f(unsigned short h) {
  return __uint_as_float(((unsigned int)h) << 16);
}

// ---- prep: split x into bf16 hi/lo
__global__ __launch_bounds__(256) void split_x_kernel(const float* __restrict__ x,
    unsigned short* __restrict__ hi, unsigned short* __restrict__ lo) {
  int i = blockIdx.x * 256 + threadIdx.x;
  float4 v = ((const float4*)x)[i];
  unsigned short h0 = f2bf(v.x), h1 = f2bf(v.y), h2 = f2bf(v.z), h3 = f2bf(v.w);
  ((ushort4*)hi)[i] = make_ushort4(h0, h1, h2, h3);
  ((ushort4*)lo)[i] = make_ushort4(f2bf(v.x - bf2f(h0)), f2bf(v.y - bf2f(h1)),
                                   f2bf(v.z - bf2f(h2)), f2bf(v.w - bf2f(h3)));
}

// ---- prep: split concat(Wq,Wk,Wv) into bf16 hi/lo
__global__ __launch_bounds__(256) void split_w_kernel(const float* __restrict__ Wq,
    const float* __restrict__ Wk, const float* __restrict__ Wv,
    unsigned short* __restrict__ hi, unsigned short* __restrict__ lo) {
  int i = blockIdx.x * 256 + threadIdx.x;
  int e = i * 4;
  const int per = OUT_DIM * IN_DIM;
  const float* src = (e < per) ? Wq : (e < 2 * per) ? Wk : Wv;
  int rem = (e < per) ? e : (e < 2 * per) ? e - per : e - 2 * per;
  float4 v = *(const float4*)(src + rem);
  unsigned short h0 = f2bf(v.x), h1 = f2bf(v.y), h2 = f2bf(v.z), h3 = f2bf(v.w);
  ((ushort4*)hi)[i] = make_ushort4(h0, h1, h2, h3);
  ((ushort4*)lo)[i] = make_ushort4(f2bf(v.x - bf2f(h0)), f2bf(v.y - bf2f(h1)),
                                   f2bf(v.z - bf2f(h2)), f2bf(v.w - bf2f(h3)));
}

// ---- prep: relT[kk][o] = rel[o][kk], split hi/lo bf16
__global__ __launch_bounds__(256) void relsplit_kernel(const float* __restrict__ rel,
    unsigned short* __restrict__ relThi, unsigned short* __restrict__ relTlo) {
  int idx = blockIdx.x * 256 + threadIdx.x;    // kk*768 + o, 93*256 = 23808 exact
  int kk = idx / OUT_DIM;
  int o = idx - kk * OUT_DIM;
  float v = rel[o * KWIN + kk];
  unsigned short h = f2bf(v);
  relThi[idx] = h;
  relTlo[idx] = f2bf(v - bf2f(h));
}

// =====================================================================
// GEMM: split-bf16, 8-phase pipelined (unchanged core from round 2).
// Epilogue: q,k cols -> bf16 hi/lo arrays; v cols -> transposed bf16 vT[d][s].
// =====================================================================
#define SLOT_BYTES 49152
#define BOFF 32768

#define READ_A(MI0) \
  _Pragma("unroll") for (int mi = 0; mi < 2; ++mi) \
  _Pragma("unroll") for (int ks = 0; ks < 2; ++ks) \
    af[(MI0) + mi][ks] = *(const bf16x8*)(base + aoffs[(MI0) + mi][ks]);

#define READ_B(NI0) \
  _Pragma("unroll") for (int ni = 0; ni < 2; ++ni) \
  _Pragma("unroll") for (int ks = 0; ks < 2; ++ks) \
    bfr[(NI0) + ni][ks] = *(const bf16x8*)(base + boffs[(NI0) + ni][ks]);

#define MFMA_Q(MI0, NI0) \
  __builtin_amdgcn_s_setprio(1); \
  _Pragma("unroll") for (int ks = 0; ks < 2; ++ks) \
  _Pragma("unroll") for (int mi = 0; mi < 2; ++mi) \
  _Pragma("unroll") for (int ni = 0; ni < 2; ++ni) \
    acc[(MI0) + mi][(NI0) + ni] = __builtin_amdgcn_mfma_f32_16x16x32_bf16( \
        af[(MI0) + mi][ks], bfr[(NI0) + ni][ks], acc[(MI0) + mi][(NI0) + ni], 0, 0, 0); \
  __builtin_amdgcn_s_setprio(0);

#define PHASE_SYNC() \
  __builtin_amdgcn_s_barrier(); \
  asm volatile("s_waitcnt lgkmcnt(0)" ::: "memory"); \
  __builtin_amdgcn_sched_barrier(0);

__global__ __launch_bounds__(512, 2) void gemm_kernel(
    const unsigned short* __restrict__ Ahi, const unsigned short* __restrict__ Alo,
    const unsigned short* __restrict__ Whi, const unsigned short* __restrict__ Wlo,
    unsigned short* __restrict__ qkhi, unsigned short* __restrict__ qklo,
    unsigned short* __restrict__ vTw) {
  __shared__ unsigned short lds_u16[73728];   // 147456 B = 3 slots x 48KB
  char* ldsb = (char*)lds_u16;
  const int tid = threadIdx.x;
  const int wid = tid >> 6, lane = tid & 63;

  int bid = blockIdx.x;
  int bm, ct, KT;
  if (bid < 192) { bm = bid & 15; ct = bid >> 4; KT = 24; }          // q,k cols: 3 terms
  else { int b2 = bid - 192; bm = b2 & 15; ct = 12 + (b2 >> 4); KT = 8; }  // v cols: 1 term
  const int row0 = bm << 8, col0 = ct << 7;
  const int wm = wid >> 1, wn = wid & 1;

  int aoffs[4][2], boffs[4][2];
#pragma unroll
  for (int mi = 0; mi < 4; ++mi) {
    int row = wm * 64 + mi * 16 + (lane & 15);
    int half = row >> 7, rh = row & 127;
#pragma unroll
    for (int ks = 0; ks < 2; ++ks) {
      int cb = ks * 64 + (lane >> 4) * 16;
      int O = rh * 128 + cb;
      aoffs[mi][ks] = half * 16384 + (O ^ ((O >> 3) & 0x70));
    }
  }
#pragma unroll
  for (int ni = 0; ni < 4; ++ni) {
    int row = wn * 64 + ni * 16 + (lane & 15);
#pragma unroll
    for (int ks = 0; ks < 2; ++ks) {
      int cb = ks * 64 + (lane >> 4) * 16;
      int O = row * 128 + cb;
      boffs[ni][ks] = BOFF + (O ^ ((O >> 3) & 0x70));
    }
  }

  int srow[2], scol[2];
#pragma unroll
  for (int j = 0; j < 2; ++j) {
    int L = (j << 13) | (tid << 4);
    int Ls = L ^ ((L >> 3) & 0x70);
    srow[j] = Ls >> 7;
    scol[j] = (Ls & 127) >> 1;
  }

  auto stage128 = [&](char* ldsu, const unsigned short* gsrc, int grow0, int kloc) {
#pragma unroll
    for (int j = 0; j < 2; ++j) {
      const unsigned short* g = gsrc + (size_t)(grow0 + srow[j]) * IN_DIM + kloc + scol[j];
      __builtin_amdgcn_global_load_lds((const __attribute__((address_space(1))) void*)g,
          (__attribute__((address_space(3))) void*)(ldsu + j * 8192 + wid * 1024), 16, 0, 0);
    }
  };

  f32x4 acc[4][4] = {};
  bf16x8 af[4][2], bfr[4][2];

  {
    char* s0 = ldsb;
    stage128(s0, Ahi, row0, 0);
    stage128(s0 + 16384, Ahi, row0 + 128, 0);
    stage128(s0 + BOFF, Whi, col0, 0);
    char* s1 = ldsb + SLOT_BYTES;
    stage128(s1, Ahi, row0, 64);
    stage128(s1 + 16384, Ahi, row0 + 128, 64);
    stage128(s1 + BOFF, Whi, col0, 64);
    asm volatile("s_waitcnt vmcnt(6)" ::: "memory");
    __builtin_amdgcn_s_barrier();
  }

  for (int t = 0; t < KT; ++t) {
    char* base = ldsb + (t % 3) * SLOT_BYTES;
    const int pt = t + 2;
    const bool pref = pt < KT;
    char* pbase = ldsb + (pt % 3) * SLOT_BYTES;
    const unsigned short* pA = Ahi;
    const unsigned short* pB = Whi;
    int pk = 0;
    if (pref) {
      int term = pt >> 3;
      pA = (term == 1) ? Alo : Ahi;
      pB = (term == 2) ? Wlo : Whi;
      pk = (pt & 7) << 6;
    }

    READ_A(0)
    READ_B(0)
    if (pref) stage128(pbase, pA, row0, pk);
    PHASE_SYNC()
    MFMA_Q(0, 0)
    __builtin_amdgcn_s_barrier();

    READ_B(2)
    if (pref) stage128(pbase + 16384, pA, row0 + 128, pk);
    PHASE_SYNC()
    MFMA_Q(0, 2)
    __builtin_amdgcn_s_barrier();

    READ_A(2)
    if (pref) stage128(pbase + BOFF, pB, col0, pk);
    PHASE_SYNC()
    MFMA_Q(2, 0)
    __builtin_amdgcn_s_barrier();

    MFMA_Q(2, 2)
    if (pref) { asm volatile("s_waitcnt vmcnt(6)" ::: "memory"); }
    else      { asm volatile("s_waitcnt vmcnt(0)" ::: "memory"); }
    __builtin_amdgcn_s_barrier();
  }

  const int elr = lane & 15, elg = (lane >> 4) * 4;
  if (ct < 12) {
    // q,k: split f32 acc -> bf16 hi/lo arrays [4096][1536]
#pragma unroll
    for (int mi = 0; mi < 4; ++mi)
#pragma unroll
      for (int ni = 0; ni < 4; ++ni) {
        int ncol = col0 + wn * 64 + ni * 16 + elr;
        size_t rbase = (size_t)(row0 + wm * 64 + mi * 16 + elg);
#pragma unroll
        for (int j = 0; j < 4; ++j) {
          float v = acc[mi][ni][j];
          unsigned short h = f2bf(v);
          size_t idx = (rbase + j) * QK_W + ncol;
          qkhi[idx] = h;
          qklo[idx] = f2bf(v - bf2f(h));
        }
      }
  } else {
    // v: transposed bf16 vT[d][srow], d = ncol-1536
#pragma unroll
    for (int mi = 0; mi < 4; ++mi)
#pragma unroll
      for (int ni = 0; ni < 4; ++ni) {
        int d = col0 - 1536 + wn * 64 + ni * 16 + elr;
        int srow = row0 + wm * 64 + mi * 16 + elg;
        ushort4 pk4;
        pk4.x = f2bf(acc[mi][ni][0]); pk4.y = f2bf(acc[mi][ni][1]);
        pk4.z = f2bf(acc[mi][ni][2]); pk4.w = f2bf(acc[mi][ni][3]);
        *(ushort4*)(vTw + (size_t)d * M_TOT + srow) = pk4;
      }
  }
}

// =====================================================================
// MFMA banded attention. Block = (b, g, 32-row tile), 256 thr (4 waves).
// LDS (80KB): Khi[96][128] @0 | Klo[96][128] @24576 | VT[128][64] @49152 |
//             Ab[32][64] @65536 | E f32[32][96] @69632
// E(32x96) = Q·[Kwin;rel;pad]^T  (3-term split bf16, rows = si, cols = window row)
// softmax -> attn_out + banded Ab (col = si+kk+1, matching VT base s0-16)
// out(32x128) = Ab·V via VT rows.
// =====================================================================
__global__ __launch_bounds__(256, 2) void attn_kernel(
    const unsigned short* __restrict__ qkhi, const unsigned short* __restrict__ qklo,
    const unsigned short* __restrict__ vT,
    const unsigned short* __restrict__ relThi, const unsigned short* __restrict__ relTlo,
    float* __restrict__ out, float* __restrict__ attn_out) {
  __shared__ __attribute__((aligned(16))) unsigned short smem[40960];   // 81920 B
  char* smb = (char*)smem;
  float* Elds = (float*)(smb + 69632);

  const int tid = threadIdx.x;
  const int wid = tid >> 6, lane = tid & 63;
  const int bid = blockIdx.x;            // 768 = 2*6*64
  const int tile = bid & 63;
  const int g = (bid >> 6) % NGROUP;
  const int b = bid / (64 * NGROUP);
  const int s0 = tile * 32;
  const size_t rowbase = (size_t)b * S_LEN;
  const int elr = lane & 15, elq = lane >> 4;

  // ---- stage K windows (hi & lo): rows 0..61 k-win, 62..92 rel, 93..95 zero
  auto stageK = [&](int ldsbase, const unsigned short* src, const unsigned short* relsrc) {
#pragma unroll
    for (int p = 0; p < 6; ++p) {
      int id = p * 256 + tid;            // 1536 chunks: row w (0..95) x 16 x 16B
      int w = id >> 4, cb = id & 15;
      u16x8 val = {};
      if (w < 62) {
        int r = s0 - 15 + w;
        if (r >= 0 && r < S_LEN)
          val = *(const u16x8*)(src + (size_t)(rowbase + r) * QK_W + OUT_DIM + g * DHEAD + cb * 8);
      } else if (w < 93) {
        val = *(const u16x8*)(relsrc + (w - 62) * OUT_DIM + g * DHEAD + cb * 8);
      }
      int O = w * 256 + cb * 16;
      O ^= (O >> 4) & 0x70;
      *(u16x8*)(smb + ldsbase + O) = val;
    }
  };
  stageK(0, qkhi, relThi);
  stageK(24576, qklo, relTlo);

  // ---- stage VT[128][64]: col jj <-> s = s0-16+jj (zero OOB); 16B-aligned base
  {
    const unsigned short* vsrc = vT + (size_t)g * DHEAD * M_TOT + (size_t)b * S_LEN;
#pragma unroll
    for (int p = 0; p < 4; ++p) {
      int id = p * 256 + tid;            // 1024 chunks: d (0..127) x 8 x 16B
      int d = id >> 3, cb = id & 7;
      int sl = s0 - 16 + cb * 8;
      const unsigned short* src = vsrc + (size_t)d * M_TOT;
      u16x8 val = {};
      if (sl >= 0 && sl + 7 < S_LEN) {
        val = *(const u16x8*)(src + sl);
      } else {
#pragma unroll
        for (int t = 0; t < 8; ++t) {
          int s = sl + t;
          if (s >= 0 && s < S_LEN) val[t] = src[s];
        }
      }
      int O = d * 128 + cb * 16;
      O ^= (O >> 3) & 0x70;
      *(u16x8*)(smb + 49152 + O) = val;
    }
  }
  // ---- zero Ab (one 16B chunk per thread; swizzle is bijective)
  {
    int O = tid * 16;
    O ^= (O >> 3) & 0x70;
    u16x8 z = {};
    *(u16x8*)(smb + 65536 + O) = z;
  }

  // ---- Q A-frags from global (per wave: its row-frag, all 4 k-steps, hi+lo)
  const int rf = wid & 1;                // E/PV row-frag of this wave
  const int cb3 = 3 * (wid >> 1);        // E col-frag base (0 or 3)
  bf16x8 qh[4], ql[4];
  {
    size_t qrow = rowbase + s0 + rf * 16 + elr;
    const unsigned short* qb  = qkhi + qrow * QK_W + g * DHEAD + elq * 8;
    const unsigned short* qb2 = qklo + qrow * QK_W + g * DHEAD + elq * 8;
#pragma unroll
    for (int ks = 0; ks < 4; ++ks) {
      qh[ks] = *(const bf16x8*)(qb + ks * 32);
      ql[ks] = *(const bf16x8*)(qb2 + ks * 32);
    }
  }
  __syncthreads();

  // ---- E = Q·K^T (3-term split), per wave 3 col-frags x 4 ksteps x 3 MFMA
#pragma unroll
  for (int cf = 0; cf < 3; ++cf) {
    int c = cb3 + cf;
    f32x4 ea = {};
#pragma unroll
    for (int ks = 0; ks < 4; ++ks) {
      int O = (c * 16 + elr) * 256 + ks * 64 + elq * 16;
      int Os = O ^ ((O >> 4) & 0x70);
      bf16x8 kh = *(const bf16x8*)(smb + Os);
      bf16x8 kl = *(const bf16x8*)(smb + 24576 + Os);
      ea = __builtin_amdgcn_mfma_f32_16x16x32_bf16(qh[ks], kh, ea, 0, 0, 0);
      ea = __builtin_amdgcn_mfma_f32_16x16x32_bf16(ql[ks], kh, ea, 0, 0, 0);
      ea = __builtin_amdgcn_mfma_f32_16x16x32_bf16(qh[ks], kl, ea, 0, 0, 0);
    }
#pragma unroll
    for (int j = 0; j < 4; ++j)
      Elds[(rf * 16 + elq * 4 + j) * 96 + c * 16 + elr] = ea[j];
  }
  __syncthreads();

  // ---- softmax (32-lane half-waves, lane = kk), write attn + banded Ab bf16
  {
    const int kkl = lane & 31;
    const int half = lane >> 5;
    const int kkc = (kkl < 31) ? kkl : 30;
#pragma unroll
    for (int p = 0; p < 4; ++p) {
      int si = p * 8 + wid * 2 + half;
      float e = Elds[si * 96 + si + kkc] + Elds[si * 96 + 62 + kkc];
      if (kkl == 31) e = -INFINITY;
      float m = e;
#pragma unroll
      for (int off = 16; off > 0; off >>= 1) m = fmaxf(m, __shfl_xor(m, off, 32));
      float pr = __expf(e - m);
      float sum = pr;
#pragma unroll
      for (int off = 16; off > 0; off >>= 1) sum += __shfl_xor(sum, off, 32);
      float a = pr / sum;
      if (kkl < 31) {
        attn_out[((rowbase + s0 + si) * NGROUP + g) * KWIN + kkl] = a;
        int O = si * 128 + (si + kkl + 1) * 2;   // jj = si+kk+1 matches VT base s0-16
        O ^= (O >> 3) & 0x70;
        *(unsigned short*)(smb + 65536 + O) = f2bf(a);
      }
    }
  }
  __syncthreads();

  // ---- PV: out(32x128) = Ab(32x64)·V ; per wave: row-frag rf, 4 d-col-frags
  {
    const int pcb = 4 * (wid >> 1);
    f32x4 pa[4] = {};
#pragma unroll
    for (int ks = 0; ks < 2; ++ks) {
      int AO = (rf * 16 + elr) * 128 + ks * 64 + elq * 16;
      AO ^= (AO >> 3) & 0x70;
      bf16x8 afr = *(const bf16x8*)(smb + 65536 + AO);
#pragma unroll
      for (int cf = 0; cf < 4; ++cf) {
        int VO = ((pcb + cf) * 16 + elr) * 128 + ks * 64 + elq * 16;
        VO ^= (VO >> 3) & 0x70;
        bf16x8 vfr = *(const bf16x8*)(smb + 49152 + VO);
        pa[cf] = __builtin_amdgcn_mfma_f32_16x16x32_bf16(afr, vfr, pa[cf], 0, 0, 0);
      }
    }
#pragma unroll
    for (int cf = 0; cf < 4; ++cf)
#pragma unroll
      for (int j = 0; j < 4; ++j)
        out[(rowbase + s0 + rf * 16 + elq * 4 + j) * OUT_DIM + g * DHEAD + pcb * 16 + cf * 16 + elr]
            = pa[cf][j];
  }
}

extern "C" void kernel_launch(void* const* d_in, const int* in_sizes, int n_in,
                              void* d_out, int out_size, void* d_ws, size_t ws_size,
                              hipStream_t stream) {
  const float* x   = (const float*)d_in[0];
  const float* Wq  = (const float*)d_in[1];
  const float* Wk  = (const float*)d_in[2];
  const float* Wv  = (const float*)d_in[3];
  const float* rel = (const float*)d_in[4];

  // ws layout (bytes):
  // Ahi 0 | Alo 4194304 | Whi 8388608 | Wlo 10747904 | relThi 13107200 |
  // relTlo 13154816 | qkhi 13202432 (12.58MB) | qklo 25785344 | vT 38368256 (6.29MB)
  char* ws = (char*)d_ws;
  unsigned short* Ahi    = (unsigned short*)(ws);
  unsigned short* Alo    = (unsigned short*)(ws + 4194304);
  unsigned short* Whi    = (unsigned short*)(ws + 8388608);
  unsigned short* Wlo    = (unsigned short*)(ws + 10747904);
  unsigned short* relThi = (unsigned short*)(ws + 13107200);
  unsigned short* relTlo = (unsigned short*)(ws + 13154816);
  unsigned short* qkhi   = (unsigned short*)(ws + 13202432);
  unsigned short* qklo   = (unsigned short*)(ws + 25785344);
  unsigned short* vTw    = (unsigned short*)(ws + 38368256);

  float* outp = (float*)d_out;
  float* attn = outp + (size_t)B_SZ * S_LEN * OUT_DIM;

  split_x_kernel<<<2048, 256, 0, stream>>>(x, Ahi, Alo);
  split_w_kernel<<<1152, 256, 0, stream>>>(Wq, Wk, Wv, Whi, Wlo);
  relsplit_kernel<<<93, 256, 0, stream>>>(rel, relThi, relTlo);
  gemm_kernel<<<288, 512, 0, stream>>>(Ahi, Alo, Whi, Wlo, qkhi, qklo, vTw);
  attn_kernel<<<768, 256, 0, stream>>>(qkhi, qklo, vTw, relThi, relTlo, outp, attn);
}

// Round 5
// 68.847 us; speedup vs baseline: 1.7857x; 1.0982x over previous
//
#include <hip/hip_runtime.h>
#include <hip/hip_bf16.h>

#define S_LEN 2048
#define B_SZ 2
#define IN_DIM 512
#define OUT_DIM 768
#define KWIN 31
#define PAD 15
#define NGROUP 6
#define DHEAD 128
#define M_TOT 4096          // B*S
#define N_TOT 2304          // 3*OUT
#define QK_W 1536           // qk hi/lo array width (q cols 0..767, k cols 768..1535)

typedef __attribute__((ext_vector_type(8))) __bf16 bf16x8;
typedef __attribute__((ext_vector_type(8))) unsigned short u16x8;
typedef __attribute__((ext_vector_type(4))) float f32x4;

static __device__ __forceinline__ unsigned short f2bf(float f) {
  unsigned int u = __float_as_uint(f);
  unsigned int r = (u + 0x7fffu + ((u >> 16) & 1u)) >> 16;   // RNE
  return (unsigned short)r;
}
static __device__ __forceinline__ float bf2f(unsigned short h) {
  return __uint_as_float(((unsigned int)h) << 16);
}

// ---- prep: split x into bf16 hi/lo
__global__ __launch_bounds__(256) void split_x_kernel(const float* __restrict__ x,
    unsigned short* __restrict__ hi, unsigned short* __restrict__ lo) {
  int i = blockIdx.x * 256 + threadIdx.x;
  float4 v = ((const float4*)x)[i];
  unsigned short h0 = f2bf(v.x), h1 = f2bf(v.y), h2 = f2bf(v.z), h3 = f2bf(v.w);
  ((ushort4*)hi)[i] = make_ushort4(h0, h1, h2, h3);
  ((ushort4*)lo)[i] = make_ushort4(f2bf(v.x - bf2f(h0)), f2bf(v.y - bf2f(h1)),
                                   f2bf(v.z - bf2f(h2)), f2bf(v.w - bf2f(h3)));
}

// ---- prep: split concat(Wq,Wk,Wv) into bf16 hi/lo
__global__ __launch_bounds__(256) void split_w_kernel(const float* __restrict__ Wq,
    const float* __restrict__ Wk, const float* __restrict__ Wv,
    unsigned short* __restrict__ hi, unsigned short* __restrict__ lo) {
  int i = blockIdx.x * 256 + threadIdx.x;
  int e = i * 4;
  const int per = OUT_DIM * IN_DIM;
  const float* src = (e < per) ? Wq : (e < 2 * per) ? Wk : Wv;
  int rem = (e < per) ? e : (e < 2 * per) ? e - per : e - 2 * per;
  float4 v = *(const float4*)(src + rem);
  unsigned short h0 = f2bf(v.x), h1 = f2bf(v.y), h2 = f2bf(v.z), h3 = f2bf(v.w);
  ((ushort4*)hi)[i] = make_ushort4(h0, h1, h2, h3);
  ((ushort4*)lo)[i] = make_ushort4(f2bf(v.x - bf2f(h0)), f2bf(v.y - bf2f(h1)),
                                   f2bf(v.z - bf2f(h2)), f2bf(v.w - bf2f(h3)));
}

// ---- prep: relT[kk][o] = rel[o][kk], split hi/lo bf16
__global__ __launch_bounds__(256) void relsplit_kernel(const float* __restrict__ rel,
    unsigned short* __restrict__ relThi, unsigned short* __restrict__ relTlo) {
  int idx = blockIdx.x * 256 + threadIdx.x;    // kk*768 + o, 93*256 = 23808 exact
  int kk = idx / OUT_DIM;
  int o = idx - kk * OUT_DIM;
  float v = rel[o * KWIN + kk];
  unsigned short h = f2bf(v);
  relThi[idx] = h;
  relTlo[idx] = f2bf(v - bf2f(h));
}

// =====================================================================
// GEMM v3: term-fused BK=32 pipeline. BM=256 BN=128, 512 thr (8 waves,
// 4M x 2N, per-wave 64x64). 48KB slots x 3 (144KB LDS), prefetch 2 chunks
// ahead, counted vmcnt. Swizzle for 64B rows: O ^= ((O>>7)&3)<<4.
// qk slot: Ahi@0(16K) Alo@16384(16K) Whi@32768(8K) Wlo@40960(8K)
// v  slot: Ahi@0(16K)                Whi@32768(8K)
// qk blocks (192): 16 chunks x {t0: Ahi*Whi, t1: Alo*Whi, t2: Ahi*Wlo}
// v  blocks (48):  2 col-tiles x 16 chunks, single term
// =====================================================================
#define SLOTB 49152

static __device__ __forceinline__ int swz32(int O) {
  return O ^ (((O >> 7) & 3) << 4);
}

#define PHASE_SYNC() \
  __builtin_amdgcn_s_barrier(); \
  asm volatile("s_waitcnt lgkmcnt(0)" ::: "memory"); \
  __builtin_amdgcn_sched_barrier(0);

#define MFMA16(AF, BF) \
  __builtin_amdgcn_s_setprio(1); \
  _Pragma("unroll") for (int mi = 0; mi < 4; ++mi) \
  _Pragma("unroll") for (int ni = 0; ni < 4; ++ni) \
    acc[mi][ni] = __builtin_amdgcn_mfma_f32_16x16x32_bf16( \
        AF[mi], BF[ni], acc[mi][ni], 0, 0, 0); \
  __builtin_amdgcn_s_setprio(0);

#define READ_AHI() _Pragma("unroll") for (int mi = 0; mi < 4; ++mi) ahi[mi] = *(const bf16x8*)(slot + aoff[mi]);
#define READ_ALO() _Pragma("unroll") for (int mi = 0; mi < 4; ++mi) alo[mi] = *(const bf16x8*)(slot + 16384 + aoff[mi]);
#define READ_WHI() _Pragma("unroll") for (int ni = 0; ni < 4; ++ni) whi[ni] = *(const bf16x8*)(slot + 32768 + boff[ni]);
#define READ_WLO() _Pragma("unroll") for (int ni = 0; ni < 4; ++ni) wlo[ni] = *(const bf16x8*)(slot + 40960 + boff[ni]);

__global__ __launch_bounds__(512, 2) void gemm_kernel(
    const unsigned short* __restrict__ Ahi, const unsigned short* __restrict__ Alo,
    const unsigned short* __restrict__ Whi, const unsigned short* __restrict__ Wlo,
    unsigned short* __restrict__ qkhi, unsigned short* __restrict__ qklo,
    unsigned short* __restrict__ vTw) {
  __shared__ unsigned short lds_u16[73728];   // 147456 B = 3 slots x 48KB
  char* ldsb = (char*)lds_u16;
  const int tid = threadIdx.x;
  const int wid = tid >> 6, lane = tid & 63;
  const int elr = lane & 15, elq = lane >> 4;
  const int wm = wid >> 1, wn = wid & 1;

  // frag byte offsets within regions (64B rows, swizzled)
  int aoff[4], boff[4];
#pragma unroll
  for (int mi = 0; mi < 4; ++mi)
    aoff[mi] = swz32((wm * 64 + mi * 16 + elr) * 64 + elq * 16);
#pragma unroll
  for (int ni = 0; ni < 4; ++ni)
    boff[ni] = swz32((wn * 64 + ni * 16 + elr) * 64 + elq * 16);

  // staging source coords (pre-swizzled; dest linear = tid*16 within region+8K*j)
  const int strow = tid >> 2;                                  // + j*128
  const int stcol = (((tid & 3) ^ ((tid >> 3) & 3)) << 3);     // elem col

  auto stage8k = [&](char* slot, int RO, int j, const unsigned short* src,
                     int grow0, int kloc) {
    const unsigned short* g = src + (size_t)(grow0 + j * 128 + strow) * IN_DIM + kloc + stcol;
    __builtin_amdgcn_global_load_lds((const __attribute__((address_space(1))) void*)g,
        (__attribute__((address_space(3))) void*)(slot + RO + j * 8192 + wid * 1024), 16, 0, 0);
  };

  f32x4 acc[4][4] = {};
  bf16x8 ahi[4], whi[4], alo[4], wlo[4];

  const int bid = blockIdx.x;

  if (bid < 192) {
    // ---------------- qk blocks: 3-term fused ----------------
    const int bm = bid & 15, ct = bid >> 4;
    const int row0 = bm << 8, col0 = ct << 7;

    // prologue: stage chunks 0,1
    {
      char* s0 = ldsb;
      stage8k(s0, 0, 0, Ahi, row0, 0);  stage8k(s0, 0, 1, Ahi, row0, 0);
      stage8k(s0, 16384, 0, Alo, row0, 0); stage8k(s0, 16384, 1, Alo, row0, 0);
      stage8k(s0, 32768, 0, Whi, col0, 0); stage8k(s0, 40960, 0, Wlo, col0, 0);
      char* s1 = ldsb + SLOTB;
      stage8k(s1, 0, 0, Ahi, row0, 32);  stage8k(s1, 0, 1, Ahi, row0, 32);
      stage8k(s1, 16384, 0, Alo, row0, 32); stage8k(s1, 16384, 1, Alo, row0, 32);
      stage8k(s1, 32768, 0, Whi, col0, 32); stage8k(s1, 40960, 0, Wlo, col0, 32);
      asm volatile("s_waitcnt vmcnt(6)" ::: "memory");
      __builtin_amdgcn_s_barrier();
    }

    for (int c = 0; c < 16; ++c) {
      char* slot = ldsb + (c % 3) * SLOTB;
      const int pc = c + 2;
      const bool pref = pc < 16;
      char* pslot = ldsb + (pc % 3) * SLOTB;
      const int pk = pc << 5;

      // phase 1: read Ahi+Whi frags; stage Ahi(t+2); MFMA term0
      READ_AHI()
      READ_WHI()
      if (pref) { stage8k(pslot, 0, 0, Ahi, row0, pk); stage8k(pslot, 0, 1, Ahi, row0, pk); }
      PHASE_SYNC()
      MFMA16(ahi, whi)
      __builtin_amdgcn_s_barrier();

      // phase 2: read Alo frags; stage Alo(t+2); MFMA term1
      READ_ALO()
      if (pref) { stage8k(pslot, 16384, 0, Alo, row0, pk); stage8k(pslot, 16384, 1, Alo, row0, pk); }
      PHASE_SYNC()
      MFMA16(alo, whi)
      __builtin_amdgcn_s_barrier();

      // phase 3: read Wlo frags; stage Whi+Wlo(t+2); MFMA term2; counted vmcnt
      READ_WLO()
      if (pref) { stage8k(pslot, 32768, 0, Whi, col0, pk); stage8k(pslot, 40960, 0, Wlo, col0, pk); }
      PHASE_SYNC()
      MFMA16(ahi, wlo)
      if (pref) { asm volatile("s_waitcnt vmcnt(6)" ::: "memory"); }
      else      { asm volatile("s_waitcnt vmcnt(0)" ::: "memory"); }
      __builtin_amdgcn_s_barrier();
    }

    // epilogue: split f32 acc -> bf16 hi/lo [4096][1536]
    const int elg = elq * 4;
#pragma unroll
    for (int mi = 0; mi < 4; ++mi)
#pragma unroll
      for (int ni = 0; ni < 4; ++ni) {
        int ncol = col0 + wn * 64 + ni * 16 + elr;
        size_t rbase = (size_t)(row0 + wm * 64 + mi * 16 + elg);
#pragma unroll
        for (int j = 0; j < 4; ++j) {
          float v = acc[mi][ni][j];
          unsigned short h = f2bf(v);
          size_t idx = (rbase + j) * QK_W + ncol;
          qkhi[idx] = h;
          qklo[idx] = f2bf(v - bf2f(h));
        }
      }
  } else {
    // ---------------- v blocks: single term, 2 col-tiles ----------------
    const int bid2 = bid - 192;             // 0..47
    const int bm = bid2 & 15, grp = bid2 >> 4;   // grp 0..2
    const int row0 = bm << 8;
    // chunk ci in [0,32): vt = ci>>4, kloc = (ci&15)*32, col = 1536+(grp*2+vt)*128
    auto vcol = [&](int ci) { return 1536 + ((grp * 2 + (ci >> 4)) << 7); };

    // prologue
    {
      char* s0 = ldsb;
      stage8k(s0, 0, 0, Ahi, row0, 0);  stage8k(s0, 0, 1, Ahi, row0, 0);
      stage8k(s0, 32768, 0, Whi, vcol(0), 0);
      char* s1 = ldsb + SLOTB;
      stage8k(s1, 0, 0, Ahi, row0, 32);  stage8k(s1, 0, 1, Ahi, row0, 32);
      stage8k(s1, 32768, 0, Whi, vcol(1), 32);
      asm volatile("s_waitcnt vmcnt(3)" ::: "memory");
      __builtin_amdgcn_s_barrier();
    }

    for (int ci = 0; ci < 32; ++ci) {
      char* slot = ldsb + (ci % 3) * SLOTB;
      const int pc = ci + 2;
      const bool pref = pc < 32;
      char* pslot = ldsb + (pc % 3) * SLOTB;
      const int pk = (pc & 15) << 5;

      READ_AHI()
      READ_WHI()
      if (pref) {
        stage8k(pslot, 0, 0, Ahi, row0, pk); stage8k(pslot, 0, 1, Ahi, row0, pk);
        stage8k(pslot, 32768, 0, Whi, vcol(pc), pk);
      }
      PHASE_SYNC()
      MFMA16(ahi, whi)
      if (pref) { asm volatile("s_waitcnt vmcnt(3)" ::: "memory"); }
      else      { asm volatile("s_waitcnt vmcnt(0)" ::: "memory"); }
      __builtin_amdgcn_s_barrier();

      if ((ci & 15) == 15) {
        // epilogue for tile vt: transposed bf16 vT[d][srow]
        const int col0 = vcol(ci);
        const int elg = elq * 4;
#pragma unroll
        for (int mi = 0; mi < 4; ++mi)
#pragma unroll
          for (int ni = 0; ni < 4; ++ni) {
            int d = col0 - 1536 + wn * 64 + ni * 16 + elr;
            int srw = row0 + wm * 64 + mi * 16 + elg;
            ushort4 pk4;
            pk4.x = f2bf(acc[mi][ni][0]); pk4.y = f2bf(acc[mi][ni][1]);
            pk4.z = f2bf(acc[mi][ni][2]); pk4.w = f2bf(acc[mi][ni][3]);
            *(ushort4*)(vTw + (size_t)d * M_TOT + srw) = pk4;
            acc[mi][ni] = (f32x4){0.f, 0.f, 0.f, 0.f};
          }
      }
    }
  }
}

// =====================================================================
// MFMA banded attention (unchanged from round 4).
// =====================================================================
__global__ __launch_bounds__(256, 2) void attn_kernel(
    const unsigned short* __restrict__ qkhi, const unsigned short* __restrict__ qklo,
    const unsigned short* __restrict__ vT,
    const unsigned short* __restrict__ relThi, const unsigned short* __restrict__ relTlo,
    float* __restrict__ out, float* __restrict__ attn_out) {
  __shared__ __attribute__((aligned(16))) unsigned short smem[40960];   // 81920 B
  char* smb = (char*)smem;
  float* Elds = (float*)(smb + 69632);

  const int tid = threadIdx.x;
  const int wid = tid >> 6, lane = tid & 63;
  const int bid = blockIdx.x;            // 768 = 2*6*64
  const int tile = bid & 63;
  const int g = (bid >> 6) % NGROUP;
  const int b = bid / (64 * NGROUP);
  const int s0 = tile * 32;
  const size_t rowbase = (size_t)b * S_LEN;
  const int elr = lane & 15, elq = lane >> 4;

  auto stageK = [&](int ldsbase, const unsigned short* src, const unsigned short* relsrc) {
#pragma unroll
    for (int p = 0; p < 6; ++p) {
      int id = p * 256 + tid;
      int w = id >> 4, cb = id & 15;
      u16x8 val = {};
      if (w < 62) {
        int r = s0 - 15 + w;
        if (r >= 0 && r < S_LEN)
          val = *(const u16x8*)(src + (size_t)(rowbase + r) * QK_W + OUT_DIM + g * DHEAD + cb * 8);
      } else if (w < 93) {
        val = *(const u16x8*)(relsrc + (w - 62) * OUT_DIM + g * DHEAD + cb * 8);
      }
      int O = w * 256 + cb * 16;
      O ^= (O >> 4) & 0x70;
      *(u16x8*)(smb + ldsbase + O) = val;
    }
  };
  stageK(0, qkhi, relThi);
  stageK(24576, qklo, relTlo);

  {
    const unsigned short* vsrc = vT + (size_t)g * DHEAD * M_TOT + (size_t)b * S_LEN;
#pragma unroll
    for (int p = 0; p < 4; ++p) {
      int id = p * 256 + tid;
      int d = id >> 3, cb = id & 7;
      int sl = s0 - 16 + cb * 8;
      const unsigned short* src = vsrc + (size_t)d * M_TOT;
      u16x8 val = {};
      if (sl >= 0 && sl + 7 < S_LEN) {
        val = *(const u16x8*)(src + sl);
      } else {
#pragma unroll
        for (int t = 0; t < 8; ++t) {
          int s = sl + t;
          if (s >= 0 && s < S_LEN) val[t] = src[s];
        }
      }
      int O = d * 128 + cb * 16;
      O ^= (O >> 3) & 0x70;
      *(u16x8*)(smb + 49152 + O) = val;
    }
  }
  {
    int O = tid * 16;
    O ^= (O >> 3) & 0x70;
    u16x8 z = {};
    *(u16x8*)(smb + 65536 + O) = z;
  }

  const int rf = wid & 1;
  const int cb3 = 3 * (wid >> 1);
  bf16x8 qh[4], ql[4];
  {
    size_t qrow = rowbase + s0 + rf * 16 + elr;
    const unsigned short* qb  = qkhi + qrow * QK_W + g * DHEAD + elq * 8;
    const unsigned short* qb2 = qklo + qrow * QK_W + g * DHEAD + elq * 8;
#pragma unroll
    for (int ks = 0; ks < 4; ++ks) {
      qh[ks] = *(const bf16x8*)(qb + ks * 32);
      ql[ks] = *(const bf16x8*)(qb2 + ks * 32);
    }
  }
  __syncthreads();

#pragma unroll
  for (int cf = 0; cf < 3; ++cf) {
    int c = cb3 + cf;
    f32x4 ea = {};
#pragma unroll
    for (int ks = 0; ks < 4; ++ks) {
      int O = (c * 16 + elr) * 256 + ks * 64 + elq * 16;
      int Os = O ^ ((O >> 4) & 0x70);
      bf16x8 kh = *(const bf16x8*)(smb + Os);
      bf16x8 kl = *(const bf16x8*)(smb + 24576 + Os);
      ea = __builtin_amdgcn_mfma_f32_16x16x32_bf16(qh[ks], kh, ea, 0, 0, 0);
      ea = __builtin_amdgcn_mfma_f32_16x16x32_bf16(ql[ks], kh, ea, 0, 0, 0);
      ea = __builtin_amdgcn_mfma_f32_16x16x32_bf16(qh[ks], kl, ea, 0, 0, 0);
    }
#pragma unroll
    for (int j = 0; j < 4; ++j)
      Elds[(rf * 16 + elq * 4 + j) * 96 + c * 16 + elr] = ea[j];
  }
  __syncthreads();

  {
    const int kkl = lane & 31;
    const int half = lane >> 5;
    const int kkc = (kkl < 31) ? kkl : 30;
#pragma unroll
    for (int p = 0; p < 4; ++p) {
      int si = p * 8 + wid * 2 + half;
      float e = Elds[si * 96 + si + kkc] + Elds[si * 96 + 62 + kkc];
      if (kkl == 31) e = -INFINITY;
      float m = e;
#pragma unroll
      for (int off = 16; off > 0; off >>= 1) m = fmaxf(m, __shfl_xor(m, off, 32));
      float pr = __expf(e - m);
      float sum = pr;
#pragma unroll
      for (int off = 16; off > 0; off >>= 1) sum += __shfl_xor(sum, off, 32);
      float a = pr / sum;
      if (kkl < 31) {
        attn_out[((rowbase + s0 + si) * NGROUP + g) * KWIN + kkl] = a;
        int O = si * 128 + (si + kkl + 1) * 2;
        O ^= (O >> 3) & 0x70;
        *(unsigned short*)(smb + 65536 + O) = f2bf(a);
      }
    }
  }
  __syncthreads();

  {
    const int pcb = 4 * (wid >> 1);
    f32x4 pa[4] = {};
#pragma unroll
    for (int ks = 0; ks < 2; ++ks) {
      int AO = (rf * 16 + elr) * 128 + ks * 64 + elq * 16;
      AO ^= (AO >> 3) & 0x70;
      bf16x8 afr = *(const bf16x8*)(smb + 65536 + AO);
#pragma unroll
      for (int cf = 0; cf < 4; ++cf) {
        int VO = ((pcb + cf) * 16 + elr) * 128 + ks * 64 + elq * 16;
        VO ^= (VO >> 3) & 0x70;
        bf16x8 vfr = *(const bf16x8*)(smb + 49152 + VO);
        pa[cf] = __builtin_amdgcn_mfma_f32_16x16x32_bf16(afr, vfr, pa[cf], 0, 0, 0);
      }
    }
#pragma unroll
    for (int cf = 0; cf < 4; ++cf)
#pragma unroll
      for (int j = 0; j < 4; ++j)
        out[(rowbase + s0 + rf * 16 + elq * 4 + j) * OUT_DIM + g * DHEAD + pcb * 16 + cf * 16 + elr]
            = pa[cf][j];
  }
}

extern "C" void kernel_launch(void* const* d_in, const int* in_sizes, int n_in,
                              void* d_out, int out_size, void* d_ws, size_t ws_size,
                              hipStream_t stream) {
  const float* x   = (const float*)d_in[0];
  const float* Wq  = (const float*)d_in[1];
  const float* Wk  = (const float*)d_in[2];
  const float* Wv  = (const float*)d_in[3];
  const float* rel = (const float*)d_in[4];

  char* ws = (char*)d_ws;
  unsigned short* Ahi    = (unsigned short*)(ws);
  unsigned short* Alo    = (unsigned short*)(ws + 4194304);
  unsigned short* Whi    = (unsigned short*)(ws + 8388608);
  unsigned short* Wlo    = (unsigned short*)(ws + 10747904);
  unsigned short* relThi = (unsigned short*)(ws + 13107200);
  unsigned short* relTlo = (unsigned short*)(ws + 13154816);
  unsigned short* qkhi   = (unsigned short*)(ws + 13202432);
  unsigned short* qklo   = (unsigned short*)(ws + 25785344);
  unsigned short* vTw    = (unsigned short*)(ws + 38368256);

  float* outp = (float*)d_out;
  float* attn = outp + (size_t)B_SZ * S_LEN * OUT_DIM;

  split_x_kernel<<<2048, 256, 0, stream>>>(x, Ahi, Alo);
  split_w_kernel<<<1152, 256, 0, stream>>>(Wq, Wk, Wv, Whi, Wlo);
  relsplit_kernel<<<93, 256, 0, stream>>>(rel, relThi, relTlo);
  gemm_kernel<<<240, 512, 0, stream>>>(Ahi, Alo, Whi, Wlo, qkhi, qklo, vTw);
  attn_kernel<<<768, 256, 0, stream>>>(qkhi, qklo, vTw, relThi, relTlo, outp, attn);
}

// Round 6
// 64.739 us; speedup vs baseline: 1.8991x; 1.0635x over previous
//
#include <hip/hip_runtime.h>
#include <hip/hip_bf16.h>

#define S_LEN 2048
#define B_SZ 2
#define IN_DIM 512
#define OUT_DIM 768
#define KWIN 31
#define PAD 15
#define NGROUP 6
#define DHEAD 128
#define M_TOT 4096          // B*S
#define N_TOT 2304          // 3*OUT
#define QK_W 1536           // qk hi/lo array width (q cols 0..767, k cols 768..1535)

typedef __attribute__((ext_vector_type(8))) __bf16 bf16x8;
typedef __attribute__((ext_vector_type(8))) unsigned short u16x8;
typedef __attribute__((ext_vector_type(4))) float f32x4;

static __device__ __forceinline__ unsigned short f2bf(float f) {
  unsigned int u = __float_as_uint(f);
  unsigned int r = (u + 0x7fffu + ((u >> 16) & 1u)) >> 16;   // RNE
  return (unsigned short)r;
}
static __device__ __forceinline__ float bf2f(unsigned short h) {
  return __uint_as_float(((unsigned int)h) << 16);
}

// =====================================================================
// merged prep: bid<2048 split_x | bid<3200 split_w | else relsplit
// =====================================================================
__global__ __launch_bounds__(256) void prep_kernel(
    const float* __restrict__ x,
    const float* __restrict__ Wq, const float* __restrict__ Wk, const float* __restrict__ Wv,
    const float* __restrict__ rel,
    unsigned short* __restrict__ xhi, unsigned short* __restrict__ xlo,
    unsigned short* __restrict__ whi, unsigned short* __restrict__ wlo,
    unsigned short* __restrict__ relThi, unsigned short* __restrict__ relTlo) {
  const int bid = blockIdx.x;
  const int tid = threadIdx.x;
  if (bid < 2048) {
    int i = bid * 256 + tid;
    float4 v = ((const float4*)x)[i];
    unsigned short h0 = f2bf(v.x), h1 = f2bf(v.y), h2 = f2bf(v.z), h3 = f2bf(v.w);
    ((ushort4*)xhi)[i] = make_ushort4(h0, h1, h2, h3);
    ((ushort4*)xlo)[i] = make_ushort4(f2bf(v.x - bf2f(h0)), f2bf(v.y - bf2f(h1)),
                                      f2bf(v.z - bf2f(h2)), f2bf(v.w - bf2f(h3)));
  } else if (bid < 3200) {
    int i = (bid - 2048) * 256 + tid;
    int e = i * 4;
    const int per = OUT_DIM * IN_DIM;
    const float* src = (e < per) ? Wq : (e < 2 * per) ? Wk : Wv;
    int rem = (e < per) ? e : (e < 2 * per) ? e - per : e - 2 * per;
    float4 v = *(const float4*)(src + rem);
    unsigned short h0 = f2bf(v.x), h1 = f2bf(v.y), h2 = f2bf(v.z), h3 = f2bf(v.w);
    ((ushort4*)whi)[i] = make_ushort4(h0, h1, h2, h3);
    ((ushort4*)wlo)[i] = make_ushort4(f2bf(v.x - bf2f(h0)), f2bf(v.y - bf2f(h1)),
                                      f2bf(v.z - bf2f(h2)), f2bf(v.w - bf2f(h3)));
  } else {
    int idx = (bid - 3200) * 256 + tid;    // kk*768 + o, 93*256 = 23808 exact
    int kk = idx / OUT_DIM;
    int o = idx - kk * OUT_DIM;
    float v = rel[o * KWIN + kk];
    unsigned short h = f2bf(v);
    relThi[idx] = h;
    relTlo[idx] = f2bf(v - bf2f(h));
  }
}

// =====================================================================
// GEMM v4: term-fused BK=32, SINGLE phase per chunk (2 barriers/chunk).
// BM=256 BN=128, 512 thr (8 waves, 4M x 2N, per-wave 64x64).
// 48KB slots x 3 (144KB LDS), prefetch 2 chunks ahead, counted vmcnt.
// Swizzle for 64B rows: O ^= ((O>>7)&3)<<4  (verified: 0 bank conflicts).
// qk slot: Ahi@0(16K) Alo@16384(16K) Whi@32768(8K) Wlo@40960(8K)
// v  slot: Ahi@0(16K)                Whi@32768(8K)
// qk blocks (192): 16 chunks x 48 MFMA {Ahi*Whi, Alo*Whi, Ahi*Wlo}
// v  blocks (48):  2 col-tiles x 16 chunks, single term
// =====================================================================
#define SLOTB 49152

static __device__ __forceinline__ int swz32(int O) {
  return O ^ (((O >> 7) & 3) << 4);
}

#define MFMA16(AF, BF) \
  _Pragma("unroll") for (int mi = 0; mi < 4; ++mi) \
  _Pragma("unroll") for (int ni = 0; ni < 4; ++ni) \
    acc[mi][ni] = __builtin_amdgcn_mfma_f32_16x16x32_bf16( \
        AF[mi], BF[ni], acc[mi][ni], 0, 0, 0);

#define READ_AHI() _Pragma("unroll") for (int mi = 0; mi < 4; ++mi) ahi[mi] = *(const bf16x8*)(slot + aoff[mi]);
#define READ_ALO() _Pragma("unroll") for (int mi = 0; mi < 4; ++mi) alo[mi] = *(const bf16x8*)(slot + 16384 + aoff[mi]);
#define READ_WHI() _Pragma("unroll") for (int ni = 0; ni < 4; ++ni) whi[ni] = *(const bf16x8*)(slot + 32768 + boff[ni]);
#define READ_WLO() _Pragma("unroll") for (int ni = 0; ni < 4; ++ni) wlo[ni] = *(const bf16x8*)(slot + 40960 + boff[ni]);

__global__ __launch_bounds__(512, 2) void gemm_kernel(
    const unsigned short* __restrict__ Ahi, const unsigned short* __restrict__ Alo,
    const unsigned short* __restrict__ Whi, const unsigned short* __restrict__ Wlo,
    unsigned short* __restrict__ qkhi, unsigned short* __restrict__ qklo,
    unsigned short* __restrict__ vTw) {
  __shared__ unsigned short lds_u16[73728];   // 147456 B = 3 slots x 48KB
  char* ldsb = (char*)lds_u16;
  const int tid = threadIdx.x;
  const int wid = tid >> 6, lane = tid & 63;
  const int elr = lane & 15, elq = lane >> 4;
  const int wm = wid >> 1, wn = wid & 1;

  // frag byte offsets within regions (64B rows, swizzled)
  int aoff[4], boff[4];
#pragma unroll
  for (int mi = 0; mi < 4; ++mi)
    aoff[mi] = swz32((wm * 64 + mi * 16 + elr) * 64 + elq * 16);
#pragma unroll
  for (int ni = 0; ni < 4; ++ni)
    boff[ni] = swz32((wn * 64 + ni * 16 + elr) * 64 + elq * 16);

  // staging source coords (pre-swizzled; dest linear = tid*16 within region+8K*j)
  const int strow = tid >> 2;                                  // + j*128
  const int stcol = (((tid & 3) ^ ((tid >> 3) & 3)) << 3);     // elem col

  auto stage8k = [&](char* slot, int RO, int j, const unsigned short* src,
                     int grow0, int kloc) {
    const unsigned short* g = src + (size_t)(grow0 + j * 128 + strow) * IN_DIM + kloc + stcol;
    __builtin_amdgcn_global_load_lds((const __attribute__((address_space(1))) void*)g,
        (__attribute__((address_space(3))) void*)(slot + RO + j * 8192 + wid * 1024), 16, 0, 0);
  };

  f32x4 acc[4][4] = {};
  bf16x8 ahi[4], whi[4], alo[4], wlo[4];

  const int bid = blockIdx.x;

  if (bid < 192) {
    // ---------------- qk blocks: 3-term fused, single phase/chunk ----------------
    const int bm = bid & 15, ct = bid >> 4;
    const int row0 = bm << 8, col0 = ct << 7;

    auto stageChunk = [&](int cc) {
      char* s = ldsb + (cc % 3) * SLOTB;
      const int pk = cc << 5;
      stage8k(s, 0, 0, Ahi, row0, pk);      stage8k(s, 0, 1, Ahi, row0, pk);
      stage8k(s, 16384, 0, Alo, row0, pk);  stage8k(s, 16384, 1, Alo, row0, pk);
      stage8k(s, 32768, 0, Whi, col0, pk);  stage8k(s, 40960, 0, Wlo, col0, pk);
    };

    stageChunk(0);
    stageChunk(1);
    asm volatile("s_waitcnt vmcnt(6)" ::: "memory");   // chunk 0 landed
    __builtin_amdgcn_s_barrier();

    for (int c = 0; c < 16; ++c) {
      char* slot = ldsb + (c % 3) * SLOTB;
      READ_AHI()
      READ_ALO()
      READ_WHI()
      READ_WLO()
      __builtin_amdgcn_s_barrier();                       // all waves done reading old slots
      asm volatile("s_waitcnt lgkmcnt(0)" ::: "memory");  // my frags in regs
      __builtin_amdgcn_sched_barrier(0);
      const bool pref = (c + 2) < 16;
      if (pref) stageChunk(c + 2);                        // into slot (c-1)%3: safe after barrier
      __builtin_amdgcn_sched_barrier(0);
      __builtin_amdgcn_s_setprio(1);
      MFMA16(ahi, whi)
      MFMA16(alo, whi)
      MFMA16(ahi, wlo)
      __builtin_amdgcn_s_setprio(0);
      if (pref) { asm volatile("s_waitcnt vmcnt(6)" ::: "memory"); }
      else      { asm volatile("s_waitcnt vmcnt(0)" ::: "memory"); }
      __builtin_amdgcn_s_barrier();                       // chunk c+1 visible
    }

    // epilogue: split f32 acc -> bf16 hi/lo [4096][1536]
    const int elg = elq * 4;
#pragma unroll
    for (int mi = 0; mi < 4; ++mi)
#pragma unroll
      for (int ni = 0; ni < 4; ++ni) {
        int ncol = col0 + wn * 64 + ni * 16 + elr;
        size_t rbase = (size_t)(row0 + wm * 64 + mi * 16 + elg);
#pragma unroll
        for (int j = 0; j < 4; ++j) {
          float v = acc[mi][ni][j];
          unsigned short h = f2bf(v);
          size_t idx = (rbase + j) * QK_W + ncol;
          qkhi[idx] = h;
          qklo[idx] = f2bf(v - bf2f(h));
        }
      }
  } else {
    // ---------------- v blocks: single term, 2 col-tiles ----------------
    const int bid2 = bid - 192;                  // 0..47
    const int bm = bid2 & 15, grp = bid2 >> 4;   // grp 0..2
    const int row0 = bm << 8;
    auto vcol = [&](int ci) { return 1536 + ((grp * 2 + (ci >> 4)) << 7); };

    auto stageChunkV = [&](int cc) {
      char* s = ldsb + (cc % 3) * SLOTB;
      const int pk = (cc & 15) << 5;
      stage8k(s, 0, 0, Ahi, row0, pk);  stage8k(s, 0, 1, Ahi, row0, pk);
      stage8k(s, 32768, 0, Whi, vcol(cc), pk);
    };

    stageChunkV(0);
    stageChunkV(1);
    asm volatile("s_waitcnt vmcnt(3)" ::: "memory");
    __builtin_amdgcn_s_barrier();

    for (int ci = 0; ci < 32; ++ci) {
      char* slot = ldsb + (ci % 3) * SLOTB;
      READ_AHI()
      READ_WHI()
      __builtin_amdgcn_s_barrier();
      asm volatile("s_waitcnt lgkmcnt(0)" ::: "memory");
      __builtin_amdgcn_sched_barrier(0);
      const bool pref = (ci + 2) < 32;
      if (pref) stageChunkV(ci + 2);
      __builtin_amdgcn_sched_barrier(0);
      __builtin_amdgcn_s_setprio(1);
      MFMA16(ahi, whi)
      __builtin_amdgcn_s_setprio(0);
      if (pref) { asm volatile("s_waitcnt vmcnt(3)" ::: "memory"); }
      else      { asm volatile("s_waitcnt vmcnt(0)" ::: "memory"); }
      __builtin_amdgcn_s_barrier();

      if ((ci & 15) == 15) {
        // epilogue for tile: transposed bf16 vT[d][srow]
        const int col0 = vcol(ci);
        const int elg = elq * 4;
#pragma unroll
        for (int mi = 0; mi < 4; ++mi)
#pragma unroll
          for (int ni = 0; ni < 4; ++ni) {
            int d = col0 - 1536 + wn * 64 + ni * 16 + elr;
            int srw = row0 + wm * 64 + mi * 16 + elg;
            ushort4 pk4;
            pk4.x = f2bf(acc[mi][ni][0]); pk4.y = f2bf(acc[mi][ni][1]);
            pk4.z = f2bf(acc[mi][ni][2]); pk4.w = f2bf(acc[mi][ni][3]);
            *(ushort4*)(vTw + (size_t)d * M_TOT + srw) = pk4;
            acc[mi][ni] = (f32x4){0.f, 0.f, 0.f, 0.f};
          }
      }
    }
  }
}

// =====================================================================
// MFMA banded attention (unchanged from round 5).
// =====================================================================
__global__ __launch_bounds__(256, 2) void attn_kernel(
    const unsigned short* __restrict__ qkhi, const unsigned short* __restrict__ qklo,
    const unsigned short* __restrict__ vT,
    const unsigned short* __restrict__ relThi, const unsigned short* __restrict__ relTlo,
    float* __restrict__ out, float* __restrict__ attn_out) {
  __shared__ __attribute__((aligned(16))) unsigned short smem[40960];   // 81920 B
  char* smb = (char*)smem;
  float* Elds = (float*)(smb + 69632);

  const int tid = threadIdx.x;
  const int wid = tid >> 6, lane = tid & 63;
  const int bid = blockIdx.x;            // 768 = 2*6*64
  const int tile = bid & 63;
  const int g = (bid >> 6) % NGROUP;
  const int b = bid / (64 * NGROUP);
  const int s0 = tile * 32;
  const size_t rowbase = (size_t)b * S_LEN;
  const int elr = lane & 15, elq = lane >> 4;

  auto stageK = [&](int ldsbase, const unsigned short* src, const unsigned short* relsrc) {
#pragma unroll
    for (int p = 0; p < 6; ++p) {
      int id = p * 256 + tid;
      int w = id >> 4, cb = id & 15;
      u16x8 val = {};
      if (w < 62) {
        int r = s0 - 15 + w;
        if (r >= 0 && r < S_LEN)
          val = *(const u16x8*)(src + (size_t)(rowbase + r) * QK_W + OUT_DIM + g * DHEAD + cb * 8);
      } else if (w < 93) {
        val = *(const u16x8*)(relsrc + (w - 62) * OUT_DIM + g * DHEAD + cb * 8);
      }
      int O = w * 256 + cb * 16;
      O ^= (O >> 4) & 0x70;
      *(u16x8*)(smb + ldsbase + O) = val;
    }
  };
  stageK(0, qkhi, relThi);
  stageK(24576, qklo, relTlo);

  {
    const unsigned short* vsrc = vT + (size_t)g * DHEAD * M_TOT + (size_t)b * S_LEN;
#pragma unroll
    for (int p = 0; p < 4; ++p) {
      int id = p * 256 + tid;
      int d = id >> 3, cb = id & 7;
      int sl = s0 - 16 + cb * 8;
      const unsigned short* src = vsrc + (size_t)d * M_TOT;
      u16x8 val = {};
      if (sl >= 0 && sl + 7 < S_LEN) {
        val = *(const u16x8*)(src + sl);
      } else {
#pragma unroll
        for (int t = 0; t < 8; ++t) {
          int s = sl + t;
          if (s >= 0 && s < S_LEN) val[t] = src[s];
        }
      }
      int O = d * 128 + cb * 16;
      O ^= (O >> 3) & 0x70;
      *(u16x8*)(smb + 49152 + O) = val;
    }
  }
  {
    int O = tid * 16;
    O ^= (O >> 3) & 0x70;
    u16x8 z = {};
    *(u16x8*)(smb + 65536 + O) = z;
  }

  const int rf = wid & 1;
  const int cb3 = 3 * (wid >> 1);
  bf16x8 qh[4], ql[4];
  {
    size_t qrow = rowbase + s0 + rf * 16 + elr;
    const unsigned short* qb  = qkhi + qrow * QK_W + g * DHEAD + elq * 8;
    const unsigned short* qb2 = qklo + qrow * QK_W + g * DHEAD + elq * 8;
#pragma unroll
    for (int ks = 0; ks < 4; ++ks) {
      qh[ks] = *(const bf16x8*)(qb + ks * 32);
      ql[ks] = *(const bf16x8*)(qb2 + ks * 32);
    }
  }
  __syncthreads();

#pragma unroll
  for (int cf = 0; cf < 3; ++cf) {
    int c = cb3 + cf;
    f32x4 ea = {};
#pragma unroll
    for (int ks = 0; ks < 4; ++ks) {
      int O = (c * 16 + elr) * 256 + ks * 64 + elq * 16;
      int Os = O ^ ((O >> 4) & 0x70);
      bf16x8 kh = *(const bf16x8*)(smb + Os);
      bf16x8 kl = *(const bf16x8*)(smb + 24576 + Os);
      ea = __builtin_amdgcn_mfma_f32_16x16x32_bf16(qh[ks], kh, ea, 0, 0, 0);
      ea = __builtin_amdgcn_mfma_f32_16x16x32_bf16(ql[ks], kh, ea, 0, 0, 0);
      ea = __builtin_amdgcn_mfma_f32_16x16x32_bf16(qh[ks], kl, ea, 0, 0, 0);
    }
#pragma unroll
    for (int j = 0; j < 4; ++j)
      Elds[(rf * 16 + elq * 4 + j) * 96 + c * 16 + elr] = ea[j];
  }
  __syncthreads();

  {
    const int kkl = lane & 31;
    const int half = lane >> 5;
    const int kkc = (kkl < 31) ? kkl : 30;
#pragma unroll
    for (int p = 0; p < 4; ++p) {
      int si = p * 8 + wid * 2 + half;
      float e = Elds[si * 96 + si + kkc] + Elds[si * 96 + 62 + kkc];
      if (kkl == 31) e = -INFINITY;
      float m = e;
#pragma unroll
      for (int off = 16; off > 0; off >>= 1) m = fmaxf(m, __shfl_xor(m, off, 32));
      float pr = __expf(e - m);
      float sum = pr;
#pragma unroll
      for (int off = 16; off > 0; off >>= 1) sum += __shfl_xor(sum, off, 32);
      float a = pr / sum;
      if (kkl < 31) {
        attn_out[((rowbase + s0 + si) * NGROUP + g) * KWIN + kkl] = a;
        int O = si * 128 + (si + kkl + 1) * 2;
        O ^= (O >> 3) & 0x70;
        *(unsigned short*)(smb + 65536 + O) = f2bf(a);
      }
    }
  }
  __syncthreads();

  {
    const int pcb = 4 * (wid >> 1);
    f32x4 pa[4] = {};
#pragma unroll
    for (int ks = 0; ks < 2; ++ks) {
      int AO = (rf * 16 + elr) * 128 + ks * 64 + elq * 16;
      AO ^= (AO >> 3) & 0x70;
      bf16x8 afr = *(const bf16x8*)(smb + 65536 + AO);
#pragma unroll
      for (int cf = 0; cf < 4; ++cf) {
        int VO = ((pcb + cf) * 16 + elr) * 128 + ks * 64 + elq * 16;
        VO ^= (VO >> 3) & 0x70;
        bf16x8 vfr = *(const bf16x8*)(smb + 49152 + VO);
        pa[cf] = __builtin_amdgcn_mfma_f32_16x16x32_bf16(afr, vfr, pa[cf], 0, 0, 0);
      }
    }
#pragma unroll
    for (int cf = 0; cf < 4; ++cf)
#pragma unroll
      for (int j = 0; j < 4; ++j)
        out[(rowbase + s0 + rf * 16 + elq * 4 + j) * OUT_DIM + g * DHEAD + pcb * 16 + cf * 16 + elr]
            = pa[cf][j];
  }
}

extern "C" void kernel_launch(void* const* d_in, const int* in_sizes, int n_in,
                              void* d_out, int out_size, void* d_ws, size_t ws_size,
                              hipStream_t stream) {
  const float* x   = (const float*)d_in[0];
  const float* Wq  = (const float*)d_in[1];
  const float* Wk  = (const float*)d_in[2];
  const float* Wv  = (const float*)d_in[3];
  const float* rel = (const float*)d_in[4];

  char* ws = (char*)d_ws;
  unsigned short* Ahi    = (unsigned short*)(ws);
  unsigned short* Alo    = (unsigned short*)(ws + 4194304);
  unsigned short* Whi    = (unsigned short*)(ws + 8388608);
  unsigned short* Wlo    = (unsigned short*)(ws + 10747904);
  unsigned short* relThi = (unsigned short*)(ws + 13107200);
  unsigned short* relTlo = (unsigned short*)(ws + 13154816);
  unsigned short* qkhi   = (unsigned short*)(ws + 13202432);
  unsigned short* qklo   = (unsigned short*)(ws + 25785344);
  unsigned short* vTw    = (unsigned short*)(ws + 38368256);

  float* outp = (float*)d_out;
  float* attn = outp + (size_t)B_SZ * S_LEN * OUT_DIM;

  prep_kernel<<<3293, 256, 0, stream>>>(x, Wq, Wk, Wv, rel, Ahi, Alo, Whi, Wlo, relThi, relTlo);
  gemm_kernel<<<240, 512, 0, stream>>>(Ahi, Alo, Whi, Wlo, qkhi, qklo, vTw);
  attn_kernel<<<768, 256, 0, stream>>>(qkhi, qklo, vTw, relThi, relTlo, outp, attn);
}

// Round 7
// 56.642 us; speedup vs baseline: 2.1705x; 1.1429x over previous
//
#include <hip/hip_runtime.h>
#include <hip/hip_bf16.h>

#define S_LEN 2048
#define B_SZ 2
#define IN_DIM 512
#define OUT_DIM 768
#define KWIN 31
#define PAD 15
#define NGROUP 6
#define DHEAD 128
#define M_TOT 4096          // B*S
#define N_TOT 2304          // 3*OUT
#define QK_W 1536           // qk hi/lo array width (q cols 0..767, k cols 768..1535)

typedef __attribute__((ext_vector_type(8))) __bf16 bf16x8;
typedef __attribute__((ext_vector_type(8))) unsigned short u16x8;
typedef __attribute__((ext_vector_type(4))) float f32x4;

static __device__ __forceinline__ unsigned short f2bf(float f) {
  unsigned int u = __float_as_uint(f);
  unsigned int r = (u + 0x7fffu + ((u >> 16) & 1u)) >> 16;   // RNE
  return (unsigned short)r;
}
static __device__ __forceinline__ float bf2f(unsigned short h) {
  return __uint_as_float(((unsigned int)h) << 16);
}

// =====================================================================
// merged prep: bid<2048 split_x | bid<3200 split_w | bid<3293 relsplit |
// bid==3293 zero-page init (256B zeros for attn DMA OOB lanes)
// =====================================================================
__global__ __launch_bounds__(256) void prep_kernel(
    const float* __restrict__ x,
    const float* __restrict__ Wq, const float* __restrict__ Wk, const float* __restrict__ Wv,
    const float* __restrict__ rel,
    unsigned short* __restrict__ xhi, unsigned short* __restrict__ xlo,
    unsigned short* __restrict__ whi, unsigned short* __restrict__ wlo,
    unsigned short* __restrict__ relThi, unsigned short* __restrict__ relTlo,
    unsigned short* __restrict__ zpage) {
  const int bid = blockIdx.x;
  const int tid = threadIdx.x;
  if (bid < 2048) {
    int i = bid * 256 + tid;
    float4 v = ((const float4*)x)[i];
    unsigned short h0 = f2bf(v.x), h1 = f2bf(v.y), h2 = f2bf(v.z), h3 = f2bf(v.w);
    ((ushort4*)xhi)[i] = make_ushort4(h0, h1, h2, h3);
    ((ushort4*)xlo)[i] = make_ushort4(f2bf(v.x - bf2f(h0)), f2bf(v.y - bf2f(h1)),
                                      f2bf(v.z - bf2f(h2)), f2bf(v.w - bf2f(h3)));
  } else if (bid < 3200) {
    int i = (bid - 2048) * 256 + tid;
    int e = i * 4;
    const int per = OUT_DIM * IN_DIM;
    const float* src = (e < per) ? Wq : (e < 2 * per) ? Wk : Wv;
    int rem = (e < per) ? e : (e < 2 * per) ? e - per : e - 2 * per;
    float4 v = *(const float4*)(src + rem);
    unsigned short h0 = f2bf(v.x), h1 = f2bf(v.y), h2 = f2bf(v.z), h3 = f2bf(v.w);
    ((ushort4*)whi)[i] = make_ushort4(h0, h1, h2, h3);
    ((ushort4*)wlo)[i] = make_ushort4(f2bf(v.x - bf2f(h0)), f2bf(v.y - bf2f(h1)),
                                      f2bf(v.z - bf2f(h2)), f2bf(v.w - bf2f(h3)));
  } else if (bid < 3293) {
    int idx = (bid - 3200) * 256 + tid;    // kk*768 + o, 93*256 = 23808 exact
    int kk = idx / OUT_DIM;
    int o = idx - kk * OUT_DIM;
    float v = rel[o * KWIN + kk];
    unsigned short h = f2bf(v);
    relThi[idx] = h;
    relTlo[idx] = f2bf(v - bf2f(h));
  } else {
    if (tid < 128) zpage[tid] = 0;         // 256 B zeros
  }
}

// =====================================================================
// GEMM v5: term-fused BK=32, ONE barrier per chunk.
// BM=256 BN=128, 512 thr (8 waves, 4M x 2N, per-wave 64x64).
// 48KB slots x 3 (144KB LDS), prefetch 2 chunks ahead, counted vmcnt.
// Swizzle for 64B rows: O ^= ((O>>7)&3)<<4  (verified: 0 bank conflicts).
// qk slot: Ahi@0(16K) Alo@16384(16K) Whi@32768(8K) Wlo@40960(8K)
// v  slot: Ahi@0(16K)                Whi@32768(8K)
// =====================================================================
#define SLOTB 49152

static __device__ __forceinline__ int swz32(int O) {
  return O ^ (((O >> 7) & 3) << 4);
}

#define MFMA16(AF, BF) \
  _Pragma("unroll") for (int mi = 0; mi < 4; ++mi) \
  _Pragma("unroll") for (int ni = 0; ni < 4; ++ni) \
    acc[mi][ni] = __builtin_amdgcn_mfma_f32_16x16x32_bf16( \
        AF[mi], BF[ni], acc[mi][ni], 0, 0, 0);

#define READ_AHI() _Pragma("unroll") for (int mi = 0; mi < 4; ++mi) ahi[mi] = *(const bf16x8*)(slot + aoff[mi]);
#define READ_ALO() _Pragma("unroll") for (int mi = 0; mi < 4; ++mi) alo[mi] = *(const bf16x8*)(slot + 16384 + aoff[mi]);
#define READ_WHI() _Pragma("unroll") for (int ni = 0; ni < 4; ++ni) whi[ni] = *(const bf16x8*)(slot + 32768 + boff[ni]);
#define READ_WLO() _Pragma("unroll") for (int ni = 0; ni < 4; ++ni) wlo[ni] = *(const bf16x8*)(slot + 40960 + boff[ni]);

#define END_BARRIER() \
  __builtin_amdgcn_s_barrier(); \
  asm volatile("" ::: "memory");

__global__ __launch_bounds__(512, 2) void gemm_kernel(
    const unsigned short* __restrict__ Ahi, const unsigned short* __restrict__ Alo,
    const unsigned short* __restrict__ Whi, const unsigned short* __restrict__ Wlo,
    unsigned short* __restrict__ qkhi, unsigned short* __restrict__ qklo,
    unsigned short* __restrict__ vTw) {
  __shared__ unsigned short lds_u16[73728];   // 147456 B = 3 slots x 48KB
  char* ldsb = (char*)lds_u16;
  const int tid = threadIdx.x;
  const int wid = tid >> 6, lane = tid & 63;
  const int elr = lane & 15, elq = lane >> 4;
  const int wm = wid >> 1, wn = wid & 1;

  // frag byte offsets within regions (64B rows, swizzled)
  int aoff[4], boff[4];
#pragma unroll
  for (int mi = 0; mi < 4; ++mi)
    aoff[mi] = swz32((wm * 64 + mi * 16 + elr) * 64 + elq * 16);
#pragma unroll
  for (int ni = 0; ni < 4; ++ni)
    boff[ni] = swz32((wn * 64 + ni * 16 + elr) * 64 + elq * 16);

  // staging source coords (pre-swizzled; dest linear = tid*16 within region+8K*j)
  const int strow = tid >> 2;                                  // + j*128
  const int stcol = (((tid & 3) ^ ((tid >> 3) & 3)) << 3);     // elem col

  auto stage8k = [&](char* slot, int RO, int j, const unsigned short* src,
                     int grow0, int kloc) {
    const unsigned short* g = src + (size_t)(grow0 + j * 128 + strow) * IN_DIM + kloc + stcol;
    __builtin_amdgcn_global_load_lds((const __attribute__((address_space(1))) void*)g,
        (__attribute__((address_space(3))) void*)(slot + RO + j * 8192 + wid * 1024), 16, 0, 0);
  };

  f32x4 acc[4][4] = {};
  bf16x8 ahi[4], whi[4], alo[4], wlo[4];

  const int bid = blockIdx.x;

  if (bid < 192) {
    // ---------------- qk blocks: 3-term fused, 1 barrier/chunk ----------------
    const int bm = bid & 15, ct = bid >> 4;
    const int row0 = bm << 8, col0 = ct << 7;

    auto stageChunk = [&](int cc) {
      char* s = ldsb + (cc % 3) * SLOTB;
      const int pk = cc << 5;
      stage8k(s, 0, 0, Ahi, row0, pk);      stage8k(s, 0, 1, Ahi, row0, pk);
      stage8k(s, 16384, 0, Alo, row0, pk);  stage8k(s, 16384, 1, Alo, row0, pk);
      stage8k(s, 32768, 0, Whi, col0, pk);  stage8k(s, 40960, 0, Wlo, col0, pk);
    };

    stageChunk(0);
    stageChunk(1);
    asm volatile("s_waitcnt vmcnt(6)" ::: "memory");   // chunk 0 landed
    END_BARRIER()

    for (int c = 0; c < 16; ++c) {
      char* slot = ldsb + (c % 3) * SLOTB;
      READ_AHI()
      READ_WHI()
      READ_ALO()
      READ_WLO()
      const bool pref = (c + 2) < 16;
      if (pref) stageChunk(c + 2);          // slot (c-1)%3: all waves read it pre-barrier(c-1)
      __builtin_amdgcn_s_setprio(1);
      MFMA16(ahi, whi)
      MFMA16(alo, whi)
      MFMA16(ahi, wlo)
      __builtin_amdgcn_s_setprio(0);
      if (pref) { asm volatile("s_waitcnt vmcnt(6)" ::: "memory"); }
      else      { asm volatile("s_waitcnt vmcnt(0)" ::: "memory"); }
      END_BARRIER()
    }

    // epilogue: split f32 acc -> bf16 hi/lo [4096][1536]
    const int elg = elq * 4;
#pragma unroll
    for (int mi = 0; mi < 4; ++mi)
#pragma unroll
      for (int ni = 0; ni < 4; ++ni) {
        int ncol = col0 + wn * 64 + ni * 16 + elr;
        size_t rbase = (size_t)(row0 + wm * 64 + mi * 16 + elg);
#pragma unroll
        for (int j = 0; j < 4; ++j) {
          float v = acc[mi][ni][j];
          unsigned short h = f2bf(v);
          size_t idx = (rbase + j) * QK_W + ncol;
          qkhi[idx] = h;
          qklo[idx] = f2bf(v - bf2f(h));
        }
      }
  } else {
    // ---------------- v blocks: single term, 2 col-tiles, 1 barrier/chunk ----------------
    const int bid2 = bid - 192;                  // 0..47
    const int bm = bid2 & 15, grp = bid2 >> 4;   // grp 0..2
    const int row0 = bm << 8;
    auto vcol = [&](int ci) { return 1536 + ((grp * 2 + (ci >> 4)) << 7); };

    auto stageChunkV = [&](int cc) {
      char* s = ldsb + (cc % 3) * SLOTB;
      const int pk = (cc & 15) << 5;
      stage8k(s, 0, 0, Ahi, row0, pk);  stage8k(s, 0, 1, Ahi, row0, pk);
      stage8k(s, 32768, 0, Whi, vcol(cc), pk);
    };

    stageChunkV(0);
    stageChunkV(1);
    asm volatile("s_waitcnt vmcnt(3)" ::: "memory");
    END_BARRIER()

    for (int ci = 0; ci < 32; ++ci) {
      char* slot = ldsb + (ci % 3) * SLOTB;
      READ_AHI()
      READ_WHI()
      const bool pref = (ci + 2) < 32;
      if (pref) stageChunkV(ci + 2);
      __builtin_amdgcn_s_setprio(1);
      MFMA16(ahi, whi)
      __builtin_amdgcn_s_setprio(0);
      if (pref) { asm volatile("s_waitcnt vmcnt(3)" ::: "memory"); }
      else      { asm volatile("s_waitcnt vmcnt(0)" ::: "memory"); }
      END_BARRIER()

      if ((ci & 15) == 15) {
        // epilogue for tile: transposed bf16 vT[d][srow]
        const int col0 = vcol(ci);
        const int elg = elq * 4;
#pragma unroll
        for (int mi = 0; mi < 4; ++mi)
#pragma unroll
          for (int ni = 0; ni < 4; ++ni) {
            int d = col0 - 1536 + wn * 64 + ni * 16 + elr;
            int srw = row0 + wm * 64 + mi * 16 + elg;
            ushort4 pk4;
            pk4.x = f2bf(acc[mi][ni][0]); pk4.y = f2bf(acc[mi][ni][1]);
            pk4.z = f2bf(acc[mi][ni][2]); pk4.w = f2bf(acc[mi][ni][3]);
            *(ushort4*)(vTw + (size_t)d * M_TOT + srw) = pk4;
            acc[mi][ni] = (f32x4){0.f, 0.f, 0.f, 0.f};
          }
      }
    }
  }
}

// =====================================================================
// MFMA banded attention. Staging now via global_load_lds (DMA) with
// pre-swizzled per-lane global sources + zero-page for OOB lanes.
// LDS (80KB): Khi[96][128] @0 | Klo[96][128] @24576 | VT[128][64] @49152 |
//             Ab[32][64] @65536 | E f32[32][96] @69632
// Swizzle algebra: K rows are 256B => dest chunk cb gets source chunk cb^(w&7);
// VT rows are 128B => cb^(d&7).  (Identical to the read-side XOR.)
// =====================================================================
__global__ __launch_bounds__(256, 2) void attn_kernel(
    const unsigned short* __restrict__ qkhi, const unsigned short* __restrict__ qklo,
    const unsigned short* __restrict__ vT,
    const unsigned short* __restrict__ relThi, const unsigned short* __restrict__ relTlo,
    const unsigned short* __restrict__ zpage,
    float* __restrict__ out, float* __restrict__ attn_out) {
  __shared__ __attribute__((aligned(16))) unsigned short smem[40960];   // 81920 B
  char* smb = (char*)smem;
  float* Elds = (float*)(smb + 69632);

  const int tid = threadIdx.x;
  const int wid = tid >> 6, lane = tid & 63;
  const int bid = blockIdx.x;            // 768 = 2*6*64
  const int tile = bid & 63;
  const int g = (bid >> 6) % NGROUP;
  const int b = bid / (64 * NGROUP);
  const int s0 = tile * 32;
  const size_t rowbase = (size_t)b * S_LEN;
  const int elr = lane & 15, elq = lane >> 4;

  // ---- K hi/lo staging via DMA: 6 insts/array; inst i covers rows i*16+wid*4+(lane>>4)
  {
    const int wrow = wid * 4 + (lane >> 4);    // 0..15
    const int kcb = lane & 15;
#pragma unroll
    for (int arr = 0; arr < 2; ++arr) {
      const unsigned short* src = arr ? qklo : qkhi;
      const unsigned short* rsrc = arr ? relTlo : relThi;
      const int ldsbase = arr ? 24576 : 0;
#pragma unroll
      for (int i = 0; i < 6; ++i) {
        int w = i * 16 + wrow;
        int scb = (kcb ^ (w & 7)) * 8;
        const unsigned short* gp;
        if (w < 62) {
          int r = s0 - 15 + w;
          gp = (r >= 0 && r < S_LEN)
             ? src + (size_t)(rowbase + r) * QK_W + OUT_DIM + g * DHEAD + scb
             : zpage + scb;
        } else if (w < 93) {
          gp = rsrc + (w - 62) * OUT_DIM + g * DHEAD + scb;
        } else {
          gp = zpage + scb;
        }
        __builtin_amdgcn_global_load_lds((const __attribute__((address_space(1))) void*)gp,
            (__attribute__((address_space(3))) void*)(smb + ldsbase + (i * 16 + wid * 4) * 256 + (lane & 15) * 16 + (lane >> 4) * 256),
            16, 0, 0);
      }
    }
  }
  // ---- VT staging via DMA: 4 insts; inst i covers d = i*32+wid*8+(lane>>3)
  {
    const unsigned short* vsrc = vT + (size_t)g * DHEAD * M_TOT + (size_t)b * S_LEN;
    const int drow = wid * 8 + (lane >> 3);    // 0..31
    const int vcb = lane & 7;
#pragma unroll
    for (int i = 0; i < 4; ++i) {
      int d = i * 32 + drow;
      int sl = s0 - 16 + (vcb ^ (d & 7)) * 8;
      const unsigned short* gp = (sl >= 0 && sl < S_LEN)
        ? vsrc + (size_t)d * M_TOT + sl
        : zpage + (vcb ^ (d & 7)) * 8;
      __builtin_amdgcn_global_load_lds((const __attribute__((address_space(1))) void*)gp,
          (__attribute__((address_space(3))) void*)(smb + 49152 + (i * 32 + wid * 8) * 128 + (lane >> 3) * 128 + (lane & 7) * 16),
          16, 0, 0);
    }
  }
  // ---- zero Ab (one 16B chunk per thread; swizzle is bijective)
  {
    int O = tid * 16;
    O ^= (O >> 3) & 0x70;
    u16x8 z = {};
    *(u16x8*)(smb + 65536 + O) = z;
  }

  // ---- Q A-frags from global (per wave: its row-frag, all 4 k-steps, hi+lo)
  const int rf = wid & 1;                // E/PV row-frag of this wave
  const int cb3 = 3 * (wid >> 1);        // E col-frag base (0 or 3)
  bf16x8 qh[4], ql[4];
  {
    size_t qrow = rowbase + s0 + rf * 16 + elr;
    const unsigned short* qb  = qkhi + qrow * QK_W + g * DHEAD + elq * 8;
    const unsigned short* qb2 = qklo + qrow * QK_W + g * DHEAD + elq * 8;
#pragma unroll
    for (int ks = 0; ks < 4; ++ks) {
      qh[ks] = *(const bf16x8*)(qb + ks * 32);
      ql[ks] = *(const bf16x8*)(qb2 + ks * 32);
    }
  }
  __syncthreads();    // drains DMA (vmcnt 0) + lgkm; barrier

  // ---- E = Q·K^T (3-term split), per wave 3 col-frags x 4 ksteps x 3 MFMA
#pragma unroll
  for (int cf = 0; cf < 3; ++cf) {
    int c = cb3 + cf;
    f32x4 ea = {};
#pragma unroll
    for (int ks = 0; ks < 4; ++ks) {
      int O = (c * 16 + elr) * 256 + ks * 64 + elq * 16;
      int Os = O ^ ((O >> 4) & 0x70);
      bf16x8 kh = *(const bf16x8*)(smb + Os);
      bf16x8 kl = *(const bf16x8*)(smb + 24576 + Os);
      ea = __builtin_amdgcn_mfma_f32_16x16x32_bf16(qh[ks], kh, ea, 0, 0, 0);
      ea = __builtin_amdgcn_mfma_f32_16x16x32_bf16(ql[ks], kh, ea, 0, 0, 0);
      ea = __builtin_amdgcn_mfma_f32_16x16x32_bf16(qh[ks], kl, ea, 0, 0, 0);
    }
#pragma unroll
    for (int j = 0; j < 4; ++j)
      Elds[(rf * 16 + elq * 4 + j) * 96 + c * 16 + elr] = ea[j];
  }
  __syncthreads();

  // ---- softmax (32-lane half-waves, lane = kk), write attn + banded Ab bf16
  {
    const int kkl = lane & 31;
    const int half = lane >> 5;
    const int kkc = (kkl < 31) ? kkl : 30;
#pragma unroll
    for (int p = 0; p < 4; ++p) {
      int si = p * 8 + wid * 2 + half;
      float e = Elds[si * 96 + si + kkc] + Elds[si * 96 + 62 + kkc];
      if (kkl == 31) e = -INFINITY;
      float m = e;
#pragma unroll
      for (int off = 16; off > 0; off >>= 1) m = fmaxf(m, __shfl_xor(m, off, 32));
      float pr = __expf(e - m);
      float sum = pr;
#pragma unroll
      for (int off = 16; off > 0; off >>= 1) sum += __shfl_xor(sum, off, 32);
      float a = pr / sum;
      if (kkl < 31) {
        attn_out[((rowbase + s0 + si) * NGROUP + g) * KWIN + kkl] = a;
        int O = si * 128 + (si + kkl + 1) * 2;
        O ^= (O >> 3) & 0x70;
        *(unsigned short*)(smb + 65536 + O) = f2bf(a);
      }
    }
  }
  __syncthreads();

  // ---- PV: out(32x128) = Ab(32x64)·V ; per wave: row-frag rf, 4 d-col-frags
  {
    const int pcb = 4 * (wid >> 1);
    f32x4 pa[4] = {};
#pragma unroll
    for (int ks = 0; ks < 2; ++ks) {
      int AO = (rf * 16 + elr) * 128 + ks * 64 + elq * 16;
      AO ^= (AO >> 3) & 0x70;
      bf16x8 afr = *(const bf16x8*)(smb + 65536 + AO);
#pragma unroll
      for (int cf = 0; cf < 4; ++cf) {
        int VO = ((pcb + cf) * 16 + elr) * 128 + ks * 64 + elq * 16;
        VO ^= (VO >> 3) & 0x70;
        bf16x8 vfr = *(const bf16x8*)(smb + 49152 + VO);
        pa[cf] = __builtin_amdgcn_mfma_f32_16x16x32_bf16(afr, vfr, pa[cf], 0, 0, 0);
      }
    }
#pragma unroll
    for (int cf = 0; cf < 4; ++cf)
#pragma unroll
      for (int j = 0; j < 4; ++j)
        out[(rowbase + s0 + rf * 16 + elq * 4 + j) * OUT_DIM + g * DHEAD + pcb * 16 + cf * 16 + elr]
            = pa[cf][j];
  }
}

extern "C" void kernel_launch(void* const* d_in, const int* in_sizes, int n_in,
                              void* d_out, int out_size, void* d_ws, size_t ws_size,
                              hipStream_t stream) {
  const float* x   = (const float*)d_in[0];
  const float* Wq  = (const float*)d_in[1];
  const float* Wk  = (const float*)d_in[2];
  const float* Wv  = (const float*)d_in[3];
  const float* rel = (const float*)d_in[4];

  char* ws = (char*)d_ws;
  unsigned short* Ahi    = (unsigned short*)(ws);
  unsigned short* Alo    = (unsigned short*)(ws + 4194304);
  unsigned short* Whi    = (unsigned short*)(ws + 8388608);
  unsigned short* Wlo    = (unsigned short*)(ws + 10747904);
  unsigned short* relThi = (unsigned short*)(ws + 13107200);
  unsigned short* relTlo = (unsigned short*)(ws + 13154816);
  unsigned short* qkhi   = (unsigned short*)(ws + 13202432);
  unsigned short* qklo   = (unsigned short*)(ws + 25785344);
  unsigned short* vTw    = (unsigned short*)(ws + 38368256);
  unsigned short* zpage  = (unsigned short*)(ws + 44659712);   // 256 B zeros

  float* outp = (float*)d_out;
  float* attn = outp + (size_t)B_SZ * S_LEN * OUT_DIM;

  prep_kernel<<<3294, 256, 0, stream>>>(x, Wq, Wk, Wv, rel, Ahi, Alo, Whi, Wlo,
                                        relThi, relTlo, zpage);
  gemm_kernel<<<240, 512, 0, stream>>>(Ahi, Alo, Whi, Wlo, qkhi, qklo, vTw);
  attn_kernel<<<768, 256, 0, stream>>>(qkhi, qklo, vTw, relThi, relTlo, zpage, outp, attn);
}